// Round 2
// baseline (319.996 us; speedup 1.0000x reference)
//
#include <hip/hip_runtime.h>
#include <hip/hip_bf16.h>
#include <math.h>

#define Bn 8
#define Cn 96
#define Hn 128
#define Wn 128
#define PLANE (Hn*Wn)          // 16384
#define NIMG (Bn*Cn*PLANE)     // 12582912
#define EPSV 1e-5f
#define TAPN 48
#define TAPF 8
#define NXCD 8
#define PLANES_PER_XCD (Bn*Cn/NXCD)   // 96

typedef __attribute__((ext_vector_type(8))) short short8;
typedef __attribute__((ext_vector_type(4))) float floatx4;

union FragU { short8 v; uint2 u2[2]; };

// ---------------------------------------------------------------------------
// K0 (slim): merged sparse integer tap lists (zero-padded). One tiny block.
// ---------------------------------------------------------------------------
__global__ void k0_taps(
    const float* __restrict__ rm_p, const float* __restrict__ whm, const float* __restrict__ wwm,
    const float* __restrict__ rl_p, const float* __restrict__ whl, const float* __restrict__ wwl,
    int* __restrict__ cnt, int* __restrict__ offs, float* __restrict__ wts)
{
    int t = threadIdx.x;              // 0..255
    if (t >= Cn * 2) return;
    int c = t >> 1, dir = t & 1;
    for (int k = 0; k < TAPN; ++k) { offs[t * TAPN + k] = 0; wts[t * TAPN + k] = 0.f; }
    const float* tap_m = dir ? (wwm + c * 5) : (whm + c * 5);
    const float* tap_l = dir ? (wwl + c * 5) : (whl + c * 5);
    float rm = fmaxf(rm_p[0], 1.f), rl = fmaxf(rl_p[0], 1.f);
    float dense[TAPN];
    for (int k = 0; k < TAPN; ++k) dense[k] = 0.f;
    for (int pass = 0; pass < 2; ++pass) {
        float r = pass ? rl : rm;
        const float* tp = pass ? tap_l : tap_m;
        for (int i = 0; i < 5; ++i) {
            float s = (float)(i - 2) * r;
            float f = floorf(s);
            float fr = s - f;
            int fi = (int)f + 23;
            if (fi >= 0 && fi < TAPN)         dense[fi]     += tp[i] * (1.f - fr);
            if (fi + 1 >= 0 && fi + 1 < TAPN) dense[fi + 1] += tp[i] * fr;
        }
    }
    int n = 0;
    for (int k = 0; k < TAPN; ++k) {
        if (dense[k] != 0.f) {
            offs[t * TAPN + n] = k - 23;
            wts[t * TAPN + n] = dense[k];
            ++n;
        }
    }
    cnt[t] = n;
}

// ---------------------------------------------------------------------------
// K1: t = 2x + FIR(H) + FIR(W)  (bf16, layout [b][h][c][w])
//     anchor = BN_d(x + dwconv3_h + dwconv3_w)  (fp32, layout [b][c][h][w])
// XCD-locality block remap: all 16 sub-blocks of one (b,c) plane land on the
// SAME XCD consecutively (dispatch round-robins %8) -> H-tap reads hit the
// local L2 instead of missing.  (FETCH 116MB -> 25MB, verified round 1.)
// ---------------------------------------------------------------------------
__global__ __launch_bounds__(256) void k1_axial(
    const float* __restrict__ x,
    const int* __restrict__ cnt, const int* __restrict__ offs, const float* __restrict__ wts,
    const float* __restrict__ dwh, const float* __restrict__ dww,
    const float* __restrict__ dg, const float* __restrict__ db_,
    const float* __restrict__ dm, const float* __restrict__ dv,
    short* __restrict__ t_bf, float* __restrict__ anchor)
{
    __shared__ float pl[8][160];        // 16-col zero pad each side
    __shared__ int   soff[2 * TAPF];
    __shared__ float swt[2 * TAPF];
    __shared__ int   scnt[2];

    // ----- XCD-locality block remap (bijective: 8 * 96 * 16 = 12288) -----
    int d   = blockIdx.x;
    int xcd = d & (NXCD - 1);
    int kk  = d >> 3;
    int bc  = xcd * PLANES_PER_XCD + (kk >> 4);
    int hg  = kk & 15;
    int b   = bc / Cn;
    int c   = bc % Cn;
    int tid = threadIdx.x;
    int m   = tid & 31;
    int row = tid >> 5;                 // 0..7
    int h   = hg * 8 + row;

    if (tid < 2) scnt[tid] = cnt[c * 2 + tid];
    if (tid < 2 * TAPF) {
        int dir = tid >> 3, j = tid & (TAPF - 1);
        soff[tid] = offs[(c * 2 + dir) * TAPN + j];
        swt[tid]  = wts[(c * 2 + dir) * TAPN + j];
    }
    {
        int pr = tid >> 5, pp = tid & 31;
        pl[pr][pp < 16 ? pp : 128 + pp] = 0.f;
    }
    const float* plane = x + ((long)bc << 14);
    const float* rowp  = plane + (h << 7);
    float v0 = rowp[m], v1 = rowp[m + 32], v2 = rowp[m + 64], v3 = rowp[m + 96];
    pl[row][16 + m]      = v0;
    pl[row][16 + m + 32] = v1;
    pl[row][16 + m + 64] = v2;
    pl[row][16 + m + 96] = v3;
    __syncthreads();

    int cH = scnt[0], cW = scnt[1];
    float a0 = 2.f * v0, a1 = 2.f * v1, a2 = 2.f * v2, a3 = 2.f * v3;

    bool fast = (cH <= TAPF) && (cW <= TAPF);
#pragma unroll
    for (int j = 0; j < TAPF; ++j)
        fast = fast && (soff[TAPF + j] >= -16) && (soff[TAPF + j] <= 16);

    if (fast) {
#pragma unroll
        for (int j = 0; j < TAPF; ++j) {       // H taps (global; local-XCD L2)
            int y = h + soff[j];
            float wt = (y >= 0 && y < Hn) ? swt[j] : 0.f;
            y = min(max(y, 0), Hn - 1);
            const float* rp = plane + (y << 7);
            a0 += wt * rp[m];
            a1 += wt * rp[m + 32];
            a2 += wt * rp[m + 64];
            a3 += wt * rp[m + 96];
        }
#pragma unroll
        for (int j = 0; j < TAPF; ++j) {       // W taps (LDS, padded)
            int o = soff[TAPF + j];
            float wt = swt[TAPF + j];
            const float* rp = &pl[row][16 + o];
            a0 += wt * rp[m];
            a1 += wt * rp[m + 32];
            a2 += wt * rp[m + 64];
            a3 += wt * rp[m + 96];
        }
    } else {
        const int*   goH = offs + (c * 2 + 0) * TAPN;
        const float* gwH = wts  + (c * 2 + 0) * TAPN;
        const int*   goW = offs + (c * 2 + 1) * TAPN;
        const float* gwW = wts  + (c * 2 + 1) * TAPN;
        for (int j = 0; j < cH; ++j) {
            int y = h + goH[j];
            if (y >= 0 && y < Hn) {
                float wt = gwH[j];
                const float* rp = plane + (y << 7);
                a0 += wt * rp[m];
                a1 += wt * rp[m + 32];
                a2 += wt * rp[m + 64];
                a3 += wt * rp[m + 96];
            }
        }
        for (int j = 0; j < cW; ++j) {
            int o = goW[j];
            float wt = gwW[j];
            const float* rp = plane + (h << 7);
#pragma unroll
            for (int q = 0; q < 4; ++q) {
                int xw = m + 32 * q + o;
                float v = (xw >= 0 && xw < Wn) ? rp[xw] : 0.f;
                float* ap = (q == 0) ? &a0 : (q == 1) ? &a1 : (q == 2) ? &a2 : &a3;
                *ap += wt * v;
            }
        }
    }

    // ----- t (bf16) store, layout [b][h][c][w] -----
    short* tp = t_bf + (((long)(b * Hn + h) * Cn) + c) * Wn;
    {
        __hip_bfloat16 h0 = __float2bfloat16(a0), h1 = __float2bfloat16(a1);
        __hip_bfloat16 h2 = __float2bfloat16(a2), h3 = __float2bfloat16(a3);
        tp[m]      = *(short*)&h0;
        tp[m + 32] = *(short*)&h1;
        tp[m + 64] = *(short*)&h2;
        tp[m + 96] = *(short*)&h3;
    }

    // ----- anchor = BN_d(x + edges) -----
    float e0 = dwh[c * 3], e1 = dwh[c * 3 + 1], e2 = dwh[c * 3 + 2];
    float f0 = dww[c * 3], f1 = dww[c * 3 + 1], f2 = dww[c * 3 + 2];
    float dsc = dg[c] * rsqrtf(dv[c] + EPSV);
    float dof = db_[c] - dm[c] * dsc;
    const float* rup = plane + ((h > 0 ? h - 1 : 0) << 7);
    const float* rdn = plane + ((h < Hn - 1 ? h + 1 : Hn - 1) << 7);
    float u0 = h > 0 ? rup[m] : 0.f, u1 = h > 0 ? rup[m + 32] : 0.f;
    float u2 = h > 0 ? rup[m + 64] : 0.f, u3 = h > 0 ? rup[m + 96] : 0.f;
    float d0 = h < Hn - 1 ? rdn[m] : 0.f, d1 = h < Hn - 1 ? rdn[m + 32] : 0.f;
    float d2 = h < Hn - 1 ? rdn[m + 64] : 0.f, d3 = h < Hn - 1 ? rdn[m + 96] : 0.f;
    float* ap = anchor + ((long)bc << 14) + (h << 7);
#pragma unroll
    for (int q = 0; q < 4; ++q) {
        float vc = (q == 0) ? v0 : (q == 1) ? v1 : (q == 2) ? v2 : v3;
        float vu = (q == 0) ? u0 : (q == 1) ? u1 : (q == 2) ? u2 : u3;
        float vd = (q == 0) ? d0 : (q == 1) ? d1 : (q == 2) ? d2 : d3;
        float vl = pl[row][16 + m + 32 * q - 1];
        float vr = pl[row][16 + m + 32 * q + 1];
        float edges = e0 * vu + e1 * vc + e2 * vd + f0 * vl + f1 * vc + f2 * vr;
        ap[m + 32 * q] = (vc + edges) * dsc + dof;
    }
}

// ---------------------------------------------------------------------------
// K2: out = prelu( BN_f(w @ t) + anchor )  via bf16 MFMA 16x16x32.
// Block = (b, h): 96 outputs x 128 pixels. 4 waves x (6 m-tiles x 2 n-tiles).
// w_fuse fp32 -> bf16 conversion folded into the staging loop (L2-resident).
// ---------------------------------------------------------------------------
__global__ __launch_bounds__(256) void k2_pw(
    const short* __restrict__ t_bf, const float* __restrict__ anchor,
    const float* __restrict__ w_fuse,
    const float* __restrict__ bg, const float* __restrict__ bb,
    const float* __restrict__ bm, const float* __restrict__ bv,
    const float* __restrict__ act_a,
    float* __restrict__ out)
{
    __shared__ short wl[Cn * 100];       // [o][c], stride 100 shorts (200 B)
    __shared__ short tl[Wn * 100];       // [p][c], stride 100 shorts
    __shared__ float sfsc[Cn], sfof[Cn], saa[Cn];

    int tid  = threadIdx.x;
    int blk  = blockIdx.x;               // 1024
    int b    = blk >> 7;
    int h    = blk & 127;
    int lane = tid & 63;
    int wv   = tid >> 6;
    int n16  = lane & 15;
    int quad = lane >> 4;

    // stage w (fp32 -> bf16) -> LDS, u32 writes (c-contiguous)
    {
        uint* wdst = (uint*)wl;
        for (int e = tid; e < Cn * 48; e += 256) {
            int o = e / 48, cq = e - o * 48;
            float f0 = w_fuse[o * Cn + 2 * cq];
            float f1 = w_fuse[o * Cn + 2 * cq + 1];
            __hip_bfloat16 h0 = __float2bfloat16(f0);
            __hip_bfloat16 h1 = __float2bfloat16(f1);
            uint u = (uint)(*(unsigned short*)&h0) |
                     ((uint)(*(unsigned short*)&h1) << 16);
            wdst[o * 50 + cq] = u;
        }
    }
    // BN-fold + prelu params
    if (tid < Cn) {
        float s = bg[tid] * rsqrtf(bv[tid] + EPSV);
        sfsc[tid] = s;
        sfof[tid] = bb[tid] - bm[tid] * s;
        saa[tid]  = act_a[tid];
    }
    // stage t slab [96 c][128 w] -> LDS transposed [p][c] (4-channel packed b64)
    {
        const uint* trow = (const uint*)t_bf + (size_t)(b * Hn + h) * Cn * 64;
#pragma unroll
        for (int rg = 0; rg < 6; ++rg) {
            int c0 = wv * 24 + rg * 4;
            uint v0 = trow[(c0 + 0) * 64 + lane];
            uint v1 = trow[(c0 + 1) * 64 + lane];
            uint v2 = trow[(c0 + 2) * 64 + lane];
            uint v3 = trow[(c0 + 3) * 64 + lane];
            uint2 lo, hi;
            lo.x = (v0 & 0xffffu) | (v1 << 16);
            lo.y = (v2 & 0xffffu) | (v3 << 16);
            hi.x = (v0 >> 16) | (v1 & 0xffff0000u);
            hi.y = (v2 >> 16) | (v3 & 0xffff0000u);
            *(uint2*)(tl + (2 * lane) * 100 + c0)     = lo;
            *(uint2*)(tl + (2 * lane + 1) * 100 + c0) = hi;
        }
    }
    __syncthreads();

    // B fragments for this wave's two n-tiles
    FragU Bf[2][3];
#pragma unroll
    for (int nt = 0; nt < 2; ++nt) {
        int p = (wv * 2 + nt) * 16 + n16;
        const short* bp = tl + p * 100 + quad * 8;
#pragma unroll
        for (int kb = 0; kb < 3; ++kb) {
            Bf[nt][kb].u2[0] = *(const uint2*)(bp + kb * 32);
            Bf[nt][kb].u2[1] = *(const uint2*)(bp + kb * 32 + 4);
        }
    }

    floatx4 acc[6][2];
#pragma unroll
    for (int mt = 0; mt < 6; ++mt)
#pragma unroll
        for (int nt = 0; nt < 2; ++nt)
            acc[mt][nt] = (floatx4){0.f, 0.f, 0.f, 0.f};

#pragma unroll
    for (int mt = 0; mt < 6; ++mt) {
        int o = mt * 16 + n16;
        const short* apg = wl + o * 100 + quad * 8;
        FragU Af[3];
#pragma unroll
        for (int kb = 0; kb < 3; ++kb) {
            Af[kb].u2[0] = *(const uint2*)(apg + kb * 32);
            Af[kb].u2[1] = *(const uint2*)(apg + kb * 32 + 4);
        }
#pragma unroll
        for (int nt = 0; nt < 2; ++nt)
#pragma unroll
            for (int kb = 0; kb < 3; ++kb)
                acc[mt][nt] = __builtin_amdgcn_mfma_f32_16x16x32_bf16(
                    Af[kb].v, Bf[nt][kb].v, acc[mt][nt], 0, 0, 0);
    }

    // epilogue: BN_f + anchor + prelu, coalesced per quad
    long base = (long)b * Cn * PLANE + (h << 7);
#pragma unroll
    for (int mt = 0; mt < 6; ++mt) {
#pragma unroll
        for (int nt = 0; nt < 2; ++nt) {
            int p = (wv * 2 + nt) * 16 + n16;
#pragma unroll
            for (int reg = 0; reg < 4; ++reg) {
                int o = mt * 16 + quad * 4 + reg;
                long idx = base + (long)o * PLANE + p;
                float fused = acc[mt][nt][reg] * sfsc[o] + sfof[o];
                float v = fused + anchor[idx];
                out[idx] = (v >= 0.f) ? v : saa[o] * v;
            }
        }
    }
}

// ---------------------------------------------------------------------------
// K3: per-(b,c) plane: row means -> xh, column means -> xw
// ---------------------------------------------------------------------------
__global__ __launch_bounds__(256) void k3_means(
    const float* __restrict__ op, float* __restrict__ xh, float* __restrict__ xw)
{
    int bc = blockIdx.x;
    const float4* pl = (const float4*)(op + ((long)bc << 14));
    int tid = threadIdx.x;
    int wq = tid & 31;
    int hg = tid >> 5;
    __shared__ float cpart[8][Wn + 4];
    __shared__ float rpart[Hn];
    float4 csum = make_float4(0, 0, 0, 0);
#pragma unroll
    for (int k = 0; k < 16; ++k) {
        int h = hg * 16 + k;
        float4 v = pl[h * 32 + wq];
        csum.x += v.x; csum.y += v.y; csum.z += v.z; csum.w += v.w;
        float rs = v.x + v.y + v.z + v.w;
#pragma unroll
        for (int off = 16; off; off >>= 1) rs += __shfl_down(rs, off, 32);
        if (wq == 0) rpart[h] = rs * (1.f / Wn);
    }
    cpart[hg][wq * 4 + 0] = csum.x;
    cpart[hg][wq * 4 + 1] = csum.y;
    cpart[hg][wq * 4 + 2] = csum.z;
    cpart[hg][wq * 4 + 3] = csum.w;
    __syncthreads();
    if (tid < 128) {
        float s = 0.f;
#pragma unroll
        for (int g = 0; g < 8; ++g) s += cpart[g][tid];
        xw[bc * Wn + tid] = s * (1.f / Hn);
        xh[bc * Hn + tid] = rpart[tid];
    }
}

// ---------------------------------------------------------------------------
// K4: coord-attention MLP
// ---------------------------------------------------------------------------
__global__ __launch_bounds__(256) void k4_att(
    const float* __restrict__ xh, const float* __restrict__ xw,
    const float* __restrict__ w1,
    const float* __restrict__ g, const float* __restrict__ bb,
    const float* __restrict__ m, const float* __restrict__ v,
    const float* __restrict__ aa,
    const float* __restrict__ cwh, const float* __restrict__ cww,
    float* __restrict__ a_h, float* __restrict__ a_w)
{
    int b = blockIdx.x;
    int p = threadIdx.x;
    __shared__ float w1s[8 * Cn];
    __shared__ float whs[Cn * 8];
    __shared__ float wws[Cn * 8];
    for (int e = p; e < 8 * Cn; e += 256) { w1s[e] = w1[e]; whs[e] = cwh[e]; wws[e] = cww[e]; }
    __syncthreads();

    float acc[8];
#pragma unroll
    for (int i = 0; i < 8; ++i) acc[i] = 0.f;
    for (int c = 0; c < Cn; ++c) {
        float yv = (p < Hn) ? xh[(b * Cn + c) * Hn + p] : xw[(b * Cn + c) * Wn + (p - Hn)];
#pragma unroll
        for (int mip = 0; mip < 8; ++mip) acc[mip] += w1s[mip * Cn + c] * yv;
    }
    float y2[8];
#pragma unroll
    for (int mip = 0; mip < 8; ++mip) {
        float sc = g[mip] * rsqrtf(v[mip] + EPSV);
        float t = (acc[mip] - m[mip]) * sc + bb[mip];
        y2[mip] = (t >= 0.f) ? t : aa[mip] * t;
    }
    const float* wsel = (p < Hn) ? whs : wws;
    float* osel = (p < Hn) ? a_h : a_w;
    int pp = (p < Hn) ? p : p - Hn;
    for (int c = 0; c < Cn; ++c) {
        float s = 0.f;
#pragma unroll
        for (int mip = 0; mip < 8; ++mip) s += wsel[c * 8 + mip] * y2[mip];
        osel[(b * Cn + c) * Hn + pp] = 1.f / (1.f + expf(-s));
    }
}

// ---------------------------------------------------------------------------
// K5: out *= a_h[b,c,h] * a_w[b,c,w]   (in-place, float4)
// ---------------------------------------------------------------------------
__global__ __launch_bounds__(256) void k5_final(
    const float* __restrict__ a_h, const float* __restrict__ a_w,
    float* __restrict__ out)
{
    int idx = blockIdx.x * 256 + threadIdx.x;
    int e = idx * 4;
    if (e >= NIMG) return;
    int w = e & 127;
    int h = (e >> 7) & 127;
    int bc = e >> 14;
    float4 vv = *(const float4*)(out + e);
    float ah = a_h[bc * Hn + h];
    float4 aw = *(const float4*)(a_w + bc * Wn + w);
    float4 r;
    r.x = vv.x * ah * aw.x;
    r.y = vv.y * ah * aw.y;
    r.z = vv.z * ah * aw.z;
    r.w = vv.w * ah * aw.w;
    *(float4*)(out + e) = r;
}

// ---------------------------------------------------------------------------
extern "C" void kernel_launch(void* const* d_in, const int* in_sizes, int n_in,
                              void* d_out, int out_size, void* d_ws, size_t ws_size,
                              hipStream_t stream)
{
    const float* x     = (const float*)d_in[0];
    const float* r_m   = (const float*)d_in[1];
    const float* wh_m  = (const float*)d_in[2];
    const float* ww_m  = (const float*)d_in[3];
    const float* r_l   = (const float*)d_in[4];
    const float* wh_l  = (const float*)d_in[5];
    const float* ww_l  = (const float*)d_in[6];
    const float* wfuse = (const float*)d_in[7];
    const float* bnf_g = (const float*)d_in[8];
    const float* bnf_b = (const float*)d_in[9];
    const float* bnf_m = (const float*)d_in[10];
    const float* bnf_v = (const float*)d_in[11];
    const float* dg_wh = (const float*)d_in[12];
    const float* dg_ww = (const float*)d_in[13];
    const float* dg_g  = (const float*)d_in[14];
    const float* dg_b  = (const float*)d_in[15];
    const float* dg_m  = (const float*)d_in[16];
    const float* dg_v  = (const float*)d_in[17];
    const float* act_a = (const float*)d_in[18];
    const float* ca_w1 = (const float*)d_in[19];
    const float* ca_g  = (const float*)d_in[20];
    const float* ca_b  = (const float*)d_in[21];
    const float* ca_m  = (const float*)d_in[22];
    const float* ca_v  = (const float*)d_in[23];
    const float* ca_a  = (const float*)d_in[24];
    const float* ca_wh = (const float*)d_in[25];
    const float* ca_ww = (const float*)d_in[26];

    float* ws     = (float*)d_ws;
    float* anchor = ws;                          // NIMG floats
    float* xh     = anchor + (size_t)NIMG;       // 98304
    float* xw     = xh + Bn * Cn * Hn;
    float* a_h    = xw + Bn * Cn * Wn;
    float* a_w    = a_h + Bn * Cn * Hn;
    float* wts    = a_w + Bn * Cn * Wn;          // 192*48
    int*   cnt    = (int*)(wts + 2 * Cn * TAPN); // 192
    int*   offs   = cnt + 2 * Cn;                // 192*48
    short* t_bf   = (short*)(offs + 2 * Cn * TAPN); // NIMG shorts

    float* out = (float*)d_out;

    hipLaunchKernelGGL(k0_taps, dim3(1), dim3(256), 0, stream,
                       r_m, wh_m, ww_m, r_l, wh_l, ww_l, cnt, offs, wts);
    hipLaunchKernelGGL(k1_axial, dim3(Bn * Cn * 16), dim3(256), 0, stream,
                       x, cnt, offs, wts, dg_wh, dg_ww, dg_g, dg_b, dg_m, dg_v,
                       t_bf, anchor);
    hipLaunchKernelGGL(k2_pw, dim3(Bn * Hn), dim3(256), 0, stream,
                       t_bf, anchor, wfuse, bnf_g, bnf_b, bnf_m, bnf_v, act_a, out);
    hipLaunchKernelGGL(k3_means, dim3(Bn * Cn), dim3(256), 0, stream,
                       out, xh, xw);
    hipLaunchKernelGGL(k4_att, dim3(Bn), dim3(256), 0, stream,
                       xh, xw, ca_w1, ca_g, ca_b, ca_m, ca_v, ca_a, ca_wh, ca_ww,
                       a_h, a_w);
    hipLaunchKernelGGL(k5_final, dim3(NIMG / 1024), dim3(256), 0, stream,
                       a_h, a_w, out);
}

// Round 3
// 296.280 us; speedup vs baseline: 1.0800x; 1.0800x over previous
//
#include <hip/hip_runtime.h>
#include <hip/hip_bf16.h>
#include <math.h>

#define Bn 8
#define Cn 96
#define Hn 128
#define Wn 128
#define PLANE (Hn*Wn)          // 16384
#define NIMG (Bn*Cn*PLANE)     // 12582912
#define EPSV 1e-5f
#define TAPN 48
#define TAPF 8

typedef __attribute__((ext_vector_type(8))) short short8;
typedef __attribute__((ext_vector_type(4))) float floatx4;

union FragU { short8 v; uint2 u2[2]; };

// ---------------------------------------------------------------------------
// K0 (slim): merged sparse integer tap lists (zero-padded). One tiny block.
// ---------------------------------------------------------------------------
__global__ void k0_taps(
    const float* __restrict__ rm_p, const float* __restrict__ whm, const float* __restrict__ wwm,
    const float* __restrict__ rl_p, const float* __restrict__ whl, const float* __restrict__ wwl,
    int* __restrict__ cnt, int* __restrict__ offs, float* __restrict__ wts)
{
    int t = threadIdx.x;              // 0..255
    if (t >= Cn * 2) return;
    int c = t >> 1, dir = t & 1;
    for (int k = 0; k < TAPN; ++k) { offs[t * TAPN + k] = 0; wts[t * TAPN + k] = 0.f; }
    const float* tap_m = dir ? (wwm + c * 5) : (whm + c * 5);
    const float* tap_l = dir ? (wwl + c * 5) : (whl + c * 5);
    float rm = fmaxf(rm_p[0], 1.f), rl = fmaxf(rl_p[0], 1.f);
    float dense[TAPN];
    for (int k = 0; k < TAPN; ++k) dense[k] = 0.f;
    for (int pass = 0; pass < 2; ++pass) {
        float r = pass ? rl : rm;
        const float* tp = pass ? tap_l : tap_m;
        for (int i = 0; i < 5; ++i) {
            float s = (float)(i - 2) * r;
            float f = floorf(s);
            float fr = s - f;
            int fi = (int)f + 23;
            if (fi >= 0 && fi < TAPN)         dense[fi]     += tp[i] * (1.f - fr);
            if (fi + 1 >= 0 && fi + 1 < TAPN) dense[fi + 1] += tp[i] * fr;
        }
    }
    int n = 0;
    for (int k = 0; k < TAPN; ++k) {
        if (dense[k] != 0.f) {
            offs[t * TAPN + n] = k - 23;
            wts[t * TAPN + n] = dense[k];
            ++n;
        }
    }
    cnt[t] = n;
}

// ---------------------------------------------------------------------------
// K1: t = 2x + FIR(H) + FIR(W)  (bf16, layout [b][h][c][w])
//     anchor = BN_d(x + dwconv3_h + dwconv3_w)  (fp32, layout [b][c][h][w])
// One block per (b,c) plane; whole plane in LDS [128][160] (16-col zero pads).
// All tap + stencil reads come from LDS -> latency chain to L2 eliminated.
// Tap lists read via uniform scalar loads (L2-resident, no LDS staging).
// ---------------------------------------------------------------------------
__global__ __launch_bounds__(512) void k1_axial(
    const float* __restrict__ x,
    const int* __restrict__ cnt, const int* __restrict__ offs, const float* __restrict__ wts,
    const float* __restrict__ dwh, const float* __restrict__ dww,
    const float* __restrict__ dg, const float* __restrict__ db_,
    const float* __restrict__ dm, const float* __restrict__ dv,
    short* __restrict__ t_bf, float* __restrict__ anchor)
{
    __shared__ float pl[Hn][160];       // 81920 B: 16-col zero pad each side

    int bc  = blockIdx.x;               // 768
    int b   = bc / Cn;
    int c   = bc % Cn;
    int tid = threadIdx.x;

    const float* plane = x + ((long)bc << 14);

    // ----- stage whole plane (coalesced float4) -----
    const float4* p4 = (const float4*)plane;
#pragma unroll
    for (int it = 0; it < 8; ++it) {
        int idx = tid + it * 512;        // 0..4095
        int r = idx >> 5, c4 = idx & 31;
        *(float4*)&pl[r][16 + c4 * 4] = p4[idx];
    }
    // ----- zero the pads -----
#pragma unroll
    for (int it = 0; it < 2; ++it) {
        int idx = tid + it * 512;        // 0..1023
        int r = idx >> 3, pq = idx & 7;
        int col = (pq < 4) ? pq * 4 : 144 + (pq - 4) * 4;
        *(float4*)&pl[r][col] = (float4){0.f, 0.f, 0.f, 0.f};
    }

    // ----- taps: uniform loads (scalar) -----
    int cH = cnt[c * 2], cW = cnt[c * 2 + 1];
    int soH[TAPF], soW[TAPF];
    float swH[TAPF], swW[TAPF];
#pragma unroll
    for (int j = 0; j < TAPF; ++j) {
        soH[j] = offs[(c * 2) * TAPN + j];
        swH[j] = wts[(c * 2) * TAPN + j];
        soW[j] = offs[(c * 2 + 1) * TAPN + j];
        swW[j] = wts[(c * 2 + 1) * TAPN + j];
    }
    bool fast = (cH <= TAPF) && (cW <= TAPF);
#pragma unroll
    for (int j = 0; j < TAPF; ++j)
        fast = fast && (soW[j] >= -16) && (soW[j] <= 16);

    // ----- BN_d params -----
    float e0 = dwh[c * 3], e1 = dwh[c * 3 + 1], e2 = dwh[c * 3 + 2];
    float f0 = dww[c * 3], f1 = dww[c * 3 + 1], f2 = dww[c * 3 + 2];
    float dsc = dg[c] * rsqrtf(dv[c] + EPSV);
    float dof = db_[c] - dm[c] * dsc;

    __syncthreads();

    int m      = tid & 31;
    int rowgrp = tid >> 5;               // 0..15
    short* tbase = t_bf + ((long)(b * Hn) * Cn + c) * Wn;
    float* abase = anchor + ((long)bc << 14);

    for (int k = 0; k < 8; ++k) {
        int h = k * 16 + rowgrp;
        float vc0 = pl[h][16 + m];
        float vc1 = pl[h][16 + m + 32];
        float vc2 = pl[h][16 + m + 64];
        float vc3 = pl[h][16 + m + 96];
        float a0 = 2.f * vc0, a1 = 2.f * vc1, a2 = 2.f * vc2, a3 = 2.f * vc3;

        if (fast) {
#pragma unroll
            for (int j = 0; j < TAPF; ++j) {   // H taps (LDS, clamped+masked)
                int y = h + soH[j];
                float wt = (y >= 0 && y < Hn) ? swH[j] : 0.f;
                y = min(max(y, 0), Hn - 1);
                a0 += wt * pl[y][16 + m];
                a1 += wt * pl[y][16 + m + 32];
                a2 += wt * pl[y][16 + m + 64];
                a3 += wt * pl[y][16 + m + 96];
            }
#pragma unroll
            for (int j = 0; j < TAPF; ++j) {   // W taps (LDS, padded)
                int o = soW[j];
                float wt = swW[j];
                a0 += wt * pl[h][16 + m + o];
                a1 += wt * pl[h][16 + m + 32 + o];
                a2 += wt * pl[h][16 + m + 64 + o];
                a3 += wt * pl[h][16 + m + 96 + o];
            }
        } else {
            // slow fallback: correct for any runtime r (global gathers)
            const int*   goH = offs + (c * 2 + 0) * TAPN;
            const float* gwH = wts  + (c * 2 + 0) * TAPN;
            const int*   goW = offs + (c * 2 + 1) * TAPN;
            const float* gwW = wts  + (c * 2 + 1) * TAPN;
            for (int j = 0; j < cH; ++j) {
                int y = h + goH[j];
                if (y >= 0 && y < Hn) {
                    float wt = gwH[j];
                    const float* rp = plane + (y << 7);
                    a0 += wt * rp[m];
                    a1 += wt * rp[m + 32];
                    a2 += wt * rp[m + 64];
                    a3 += wt * rp[m + 96];
                }
            }
            for (int j = 0; j < cW; ++j) {
                int o = goW[j];
                float wt = gwW[j];
                const float* rp = plane + (h << 7);
#pragma unroll
                for (int q = 0; q < 4; ++q) {
                    int xw = m + 32 * q + o;
                    float v = (xw >= 0 && xw < Wn) ? rp[xw] : 0.f;
                    float* ap = (q == 0) ? &a0 : (q == 1) ? &a1 : (q == 2) ? &a2 : &a3;
                    *ap += wt * v;
                }
            }
        }

        // ----- t (bf16) store, layout [b][h][c][w] -----
        short* tp = tbase + (long)h * (Cn * Wn);
        {
            __hip_bfloat16 h0 = __float2bfloat16(a0), h1 = __float2bfloat16(a1);
            __hip_bfloat16 h2 = __float2bfloat16(a2), h3 = __float2bfloat16(a3);
            tp[m]      = *(short*)&h0;
            tp[m + 32] = *(short*)&h1;
            tp[m + 64] = *(short*)&h2;
            tp[m + 96] = *(short*)&h3;
        }

        // ----- anchor = BN_d(x + edges) -----
        int yu = (h > 0) ? h - 1 : 0;
        int yd = (h < Hn - 1) ? h + 1 : Hn - 1;
        float wu = (h > 0) ? e0 : 0.f;
        float wd = (h < Hn - 1) ? e2 : 0.f;
        float* ap = abase + (h << 7);
#pragma unroll
        for (int q = 0; q < 4; ++q) {
            int col = 16 + m + 32 * q;
            float vcq = (q == 0) ? vc0 : (q == 1) ? vc1 : (q == 2) ? vc2 : vc3;
            float vu = pl[yu][col];
            float vd = pl[yd][col];
            float vl = pl[h][col - 1];
            float vr = pl[h][col + 1];
            float edges = wu * vu + e1 * vcq + wd * vd + f0 * vl + f1 * vcq + f2 * vr;
            ap[m + 32 * q] = (vcq + edges) * dsc + dof;
        }
    }
}

// ---------------------------------------------------------------------------
// K2: out = prelu( BN_f(w @ t) + anchor )  via bf16 MFMA 16x16x32.
// Block = (b, h): 96 outputs x 128 pixels. 4 waves x (6 m-tiles x 2 n-tiles).
// w_fuse fp32 -> bf16 conversion folded into the staging loop (L2-resident).
// ---------------------------------------------------------------------------
__global__ __launch_bounds__(256) void k2_pw(
    const short* __restrict__ t_bf, const float* __restrict__ anchor,
    const float* __restrict__ w_fuse,
    const float* __restrict__ bg, const float* __restrict__ bb,
    const float* __restrict__ bm, const float* __restrict__ bv,
    const float* __restrict__ act_a,
    float* __restrict__ out)
{
    __shared__ short wl[Cn * 100];       // [o][c], stride 100 shorts (200 B)
    __shared__ short tl[Wn * 100];       // [p][c], stride 100 shorts
    __shared__ float sfsc[Cn], sfof[Cn], saa[Cn];

    int tid  = threadIdx.x;
    int blk  = blockIdx.x;               // 1024
    int b    = blk >> 7;
    int h    = blk & 127;
    int lane = tid & 63;
    int wv   = tid >> 6;
    int n16  = lane & 15;
    int quad = lane >> 4;

    // stage w (fp32 -> bf16) -> LDS, u32 writes (c-contiguous)
    {
        uint* wdst = (uint*)wl;
        for (int e = tid; e < Cn * 48; e += 256) {
            int o = e / 48, cq = e - o * 48;
            float f0 = w_fuse[o * Cn + 2 * cq];
            float f1 = w_fuse[o * Cn + 2 * cq + 1];
            __hip_bfloat16 h0 = __float2bfloat16(f0);
            __hip_bfloat16 h1 = __float2bfloat16(f1);
            uint u = (uint)(*(unsigned short*)&h0) |
                     ((uint)(*(unsigned short*)&h1) << 16);
            wdst[o * 50 + cq] = u;
        }
    }
    // BN-fold + prelu params
    if (tid < Cn) {
        float s = bg[tid] * rsqrtf(bv[tid] + EPSV);
        sfsc[tid] = s;
        sfof[tid] = bb[tid] - bm[tid] * s;
        saa[tid]  = act_a[tid];
    }
    // stage t slab [96 c][128 w] -> LDS transposed [p][c] (4-channel packed b64)
    {
        const uint* trow = (const uint*)t_bf + (size_t)(b * Hn + h) * Cn * 64;
#pragma unroll
        for (int rg = 0; rg < 6; ++rg) {
            int c0 = wv * 24 + rg * 4;
            uint v0 = trow[(c0 + 0) * 64 + lane];
            uint v1 = trow[(c0 + 1) * 64 + lane];
            uint v2 = trow[(c0 + 2) * 64 + lane];
            uint v3 = trow[(c0 + 3) * 64 + lane];
            uint2 lo, hi;
            lo.x = (v0 & 0xffffu) | (v1 << 16);
            lo.y = (v2 & 0xffffu) | (v3 << 16);
            hi.x = (v0 >> 16) | (v1 & 0xffff0000u);
            hi.y = (v2 >> 16) | (v3 & 0xffff0000u);
            *(uint2*)(tl + (2 * lane) * 100 + c0)     = lo;
            *(uint2*)(tl + (2 * lane + 1) * 100 + c0) = hi;
        }
    }
    __syncthreads();

    // B fragments for this wave's two n-tiles
    FragU Bf[2][3];
#pragma unroll
    for (int nt = 0; nt < 2; ++nt) {
        int p = (wv * 2 + nt) * 16 + n16;
        const short* bp = tl + p * 100 + quad * 8;
#pragma unroll
        for (int kb = 0; kb < 3; ++kb) {
            Bf[nt][kb].u2[0] = *(const uint2*)(bp + kb * 32);
            Bf[nt][kb].u2[1] = *(const uint2*)(bp + kb * 32 + 4);
        }
    }

    floatx4 acc[6][2];
#pragma unroll
    for (int mt = 0; mt < 6; ++mt)
#pragma unroll
        for (int nt = 0; nt < 2; ++nt)
            acc[mt][nt] = (floatx4){0.f, 0.f, 0.f, 0.f};

#pragma unroll
    for (int mt = 0; mt < 6; ++mt) {
        int o = mt * 16 + n16;
        const short* apg = wl + o * 100 + quad * 8;
        FragU Af[3];
#pragma unroll
        for (int kb = 0; kb < 3; ++kb) {
            Af[kb].u2[0] = *(const uint2*)(apg + kb * 32);
            Af[kb].u2[1] = *(const uint2*)(apg + kb * 32 + 4);
        }
#pragma unroll
        for (int nt = 0; nt < 2; ++nt)
#pragma unroll
            for (int kb = 0; kb < 3; ++kb)
                acc[mt][nt] = __builtin_amdgcn_mfma_f32_16x16x32_bf16(
                    Af[kb].v, Bf[nt][kb].v, acc[mt][nt], 0, 0, 0);
    }

    // epilogue: BN_f + anchor + prelu, coalesced per quad
    long base = (long)b * Cn * PLANE + (h << 7);
#pragma unroll
    for (int mt = 0; mt < 6; ++mt) {
#pragma unroll
        for (int nt = 0; nt < 2; ++nt) {
            int p = (wv * 2 + nt) * 16 + n16;
#pragma unroll
            for (int reg = 0; reg < 4; ++reg) {
                int o = mt * 16 + quad * 4 + reg;
                long idx = base + (long)o * PLANE + p;
                float fused = acc[mt][nt][reg] * sfsc[o] + sfof[o];
                float v = fused + anchor[idx];
                out[idx] = (v >= 0.f) ? v : saa[o] * v;
            }
        }
    }
}

// ---------------------------------------------------------------------------
// K3: per-(b,c) plane: row means -> xh, column means -> xw
// ---------------------------------------------------------------------------
__global__ __launch_bounds__(256) void k3_means(
    const float* __restrict__ op, float* __restrict__ xh, float* __restrict__ xw)
{
    int bc = blockIdx.x;
    const float4* pl = (const float4*)(op + ((long)bc << 14));
    int tid = threadIdx.x;
    int wq = tid & 31;
    int hg = tid >> 5;
    __shared__ float cpart[8][Wn + 4];
    __shared__ float rpart[Hn];
    float4 csum = make_float4(0, 0, 0, 0);
#pragma unroll
    for (int k = 0; k < 16; ++k) {
        int h = hg * 16 + k;
        float4 v = pl[h * 32 + wq];
        csum.x += v.x; csum.y += v.y; csum.z += v.z; csum.w += v.w;
        float rs = v.x + v.y + v.z + v.w;
#pragma unroll
        for (int off = 16; off; off >>= 1) rs += __shfl_down(rs, off, 32);
        if (wq == 0) rpart[h] = rs * (1.f / Wn);
    }
    cpart[hg][wq * 4 + 0] = csum.x;
    cpart[hg][wq * 4 + 1] = csum.y;
    cpart[hg][wq * 4 + 2] = csum.z;
    cpart[hg][wq * 4 + 3] = csum.w;
    __syncthreads();
    if (tid < 128) {
        float s = 0.f;
#pragma unroll
        for (int g = 0; g < 8; ++g) s += cpart[g][tid];
        xw[bc * Wn + tid] = s * (1.f / Hn);
        xh[bc * Hn + tid] = rpart[tid];
    }
}

// ---------------------------------------------------------------------------
// K4: coord-attention MLP
// ---------------------------------------------------------------------------
__global__ __launch_bounds__(256) void k4_att(
    const float* __restrict__ xh, const float* __restrict__ xw,
    const float* __restrict__ w1,
    const float* __restrict__ g, const float* __restrict__ bb,
    const float* __restrict__ m, const float* __restrict__ v,
    const float* __restrict__ aa,
    const float* __restrict__ cwh, const float* __restrict__ cww,
    float* __restrict__ a_h, float* __restrict__ a_w)
{
    int b = blockIdx.x;
    int p = threadIdx.x;
    __shared__ float w1s[8 * Cn];
    __shared__ float whs[Cn * 8];
    __shared__ float wws[Cn * 8];
    for (int e = p; e < 8 * Cn; e += 256) { w1s[e] = w1[e]; whs[e] = cwh[e]; wws[e] = cww[e]; }
    __syncthreads();

    float acc[8];
#pragma unroll
    for (int i = 0; i < 8; ++i) acc[i] = 0.f;
    for (int c = 0; c < Cn; ++c) {
        float yv = (p < Hn) ? xh[(b * Cn + c) * Hn + p] : xw[(b * Cn + c) * Wn + (p - Hn)];
#pragma unroll
        for (int mip = 0; mip < 8; ++mip) acc[mip] += w1s[mip * Cn + c] * yv;
    }
    float y2[8];
#pragma unroll
    for (int mip = 0; mip < 8; ++mip) {
        float sc = g[mip] * rsqrtf(v[mip] + EPSV);
        float t = (acc[mip] - m[mip]) * sc + bb[mip];
        y2[mip] = (t >= 0.f) ? t : aa[mip] * t;
    }
    const float* wsel = (p < Hn) ? whs : wws;
    float* osel = (p < Hn) ? a_h : a_w;
    int pp = (p < Hn) ? p : p - Hn;
    for (int c = 0; c < Cn; ++c) {
        float s = 0.f;
#pragma unroll
        for (int mip = 0; mip < 8; ++mip) s += wsel[c * 8 + mip] * y2[mip];
        osel[(b * Cn + c) * Hn + pp] = 1.f / (1.f + expf(-s));
    }
}

// ---------------------------------------------------------------------------
// K5: out *= a_h[b,c,h] * a_w[b,c,w]   (in-place, float4)
// ---------------------------------------------------------------------------
__global__ __launch_bounds__(256) void k5_final(
    const float* __restrict__ a_h, const float* __restrict__ a_w,
    float* __restrict__ out)
{
    int idx = blockIdx.x * 256 + threadIdx.x;
    int e = idx * 4;
    if (e >= NIMG) return;
    int w = e & 127;
    int h = (e >> 7) & 127;
    int bc = e >> 14;
    float4 vv = *(const float4*)(out + e);
    float ah = a_h[bc * Hn + h];
    float4 aw = *(const float4*)(a_w + bc * Wn + w);
    float4 r;
    r.x = vv.x * ah * aw.x;
    r.y = vv.y * ah * aw.y;
    r.z = vv.z * ah * aw.z;
    r.w = vv.w * ah * aw.w;
    *(float4*)(out + e) = r;
}

// ---------------------------------------------------------------------------
extern "C" void kernel_launch(void* const* d_in, const int* in_sizes, int n_in,
                              void* d_out, int out_size, void* d_ws, size_t ws_size,
                              hipStream_t stream)
{
    const float* x     = (const float*)d_in[0];
    const float* r_m   = (const float*)d_in[1];
    const float* wh_m  = (const float*)d_in[2];
    const float* ww_m  = (const float*)d_in[3];
    const float* r_l   = (const float*)d_in[4];
    const float* wh_l  = (const float*)d_in[5];
    const float* ww_l  = (const float*)d_in[6];
    const float* wfuse = (const float*)d_in[7];
    const float* bnf_g = (const float*)d_in[8];
    const float* bnf_b = (const float*)d_in[9];
    const float* bnf_m = (const float*)d_in[10];
    const float* bnf_v = (const float*)d_in[11];
    const float* dg_wh = (const float*)d_in[12];
    const float* dg_ww = (const float*)d_in[13];
    const float* dg_g  = (const float*)d_in[14];
    const float* dg_b  = (const float*)d_in[15];
    const float* dg_m  = (const float*)d_in[16];
    const float* dg_v  = (const float*)d_in[17];
    const float* act_a = (const float*)d_in[18];
    const float* ca_w1 = (const float*)d_in[19];
    const float* ca_g  = (const float*)d_in[20];
    const float* ca_b  = (const float*)d_in[21];
    const float* ca_m  = (const float*)d_in[22];
    const float* ca_v  = (const float*)d_in[23];
    const float* ca_a  = (const float*)d_in[24];
    const float* ca_wh = (const float*)d_in[25];
    const float* ca_ww = (const float*)d_in[26];

    float* ws     = (float*)d_ws;
    float* anchor = ws;                          // NIMG floats
    float* xh     = anchor + (size_t)NIMG;       // 98304
    float* xw     = xh + Bn * Cn * Hn;
    float* a_h    = xw + Bn * Cn * Wn;
    float* a_w    = a_h + Bn * Cn * Hn;
    float* wts    = a_w + Bn * Cn * Wn;          // 192*48
    int*   cnt    = (int*)(wts + 2 * Cn * TAPN); // 192
    int*   offs   = cnt + 2 * Cn;                // 192*48
    short* t_bf   = (short*)(offs + 2 * Cn * TAPN); // NIMG shorts

    float* out = (float*)d_out;

    hipLaunchKernelGGL(k0_taps, dim3(1), dim3(256), 0, stream,
                       r_m, wh_m, ww_m, r_l, wh_l, ww_l, cnt, offs, wts);
    hipLaunchKernelGGL(k1_axial, dim3(Bn * Cn), dim3(512), 0, stream,
                       x, cnt, offs, wts, dg_wh, dg_ww, dg_g, dg_b, dg_m, dg_v,
                       t_bf, anchor);
    hipLaunchKernelGGL(k2_pw, dim3(Bn * Hn), dim3(256), 0, stream,
                       t_bf, anchor, wfuse, bnf_g, bnf_b, bnf_m, bnf_v, act_a, out);
    hipLaunchKernelGGL(k3_means, dim3(Bn * Cn), dim3(256), 0, stream,
                       out, xh, xw);
    hipLaunchKernelGGL(k4_att, dim3(Bn), dim3(256), 0, stream,
                       xh, xw, ca_w1, ca_g, ca_b, ca_m, ca_v, ca_a, ca_wh, ca_ww,
                       a_h, a_w);
    hipLaunchKernelGGL(k5_final, dim3(NIMG / 1024), dim3(256), 0, stream,
                       a_h, a_w, out);
}

// Round 4
// 257.201 us; speedup vs baseline: 1.2441x; 1.1519x over previous
//
#include <hip/hip_runtime.h>
#include <hip/hip_bf16.h>
#include <math.h>

#define Bn 8
#define Cn 96
#define Hn 128
#define Wn 128
#define PLANE (Hn*Wn)          // 16384
#define NIMG (Bn*Cn*PLANE)     // 12582912
#define EPSV 1e-5f
#define TAPN 48
#define TAPF 8

typedef __attribute__((ext_vector_type(8))) short short8;
typedef __attribute__((ext_vector_type(4))) float floatx4;

union FragU { short8 v; uint2 u2[2]; };

// ---------------------------------------------------------------------------
// K0 (slim): merged sparse integer tap lists (zero-padded). One tiny block.
// ---------------------------------------------------------------------------
__global__ void k0_taps(
    const float* __restrict__ rm_p, const float* __restrict__ whm, const float* __restrict__ wwm,
    const float* __restrict__ rl_p, const float* __restrict__ whl, const float* __restrict__ wwl,
    int* __restrict__ cnt, int* __restrict__ offs, float* __restrict__ wts)
{
    int t = threadIdx.x;              // 0..255
    if (t >= Cn * 2) return;
    int c = t >> 1, dir = t & 1;
    for (int k = 0; k < TAPN; ++k) { offs[t * TAPN + k] = 0; wts[t * TAPN + k] = 0.f; }
    const float* tap_m = dir ? (wwm + c * 5) : (whm + c * 5);
    const float* tap_l = dir ? (wwl + c * 5) : (whl + c * 5);
    float rm = fmaxf(rm_p[0], 1.f), rl = fmaxf(rl_p[0], 1.f);
    float dense[TAPN];
    for (int k = 0; k < TAPN; ++k) dense[k] = 0.f;
    for (int pass = 0; pass < 2; ++pass) {
        float r = pass ? rl : rm;
        const float* tp = pass ? tap_l : tap_m;
        for (int i = 0; i < 5; ++i) {
            float s = (float)(i - 2) * r;
            float f = floorf(s);
            float fr = s - f;
            int fi = (int)f + 23;
            if (fi >= 0 && fi < TAPN)         dense[fi]     += tp[i] * (1.f - fr);
            if (fi + 1 >= 0 && fi + 1 < TAPN) dense[fi + 1] += tp[i] * fr;
        }
    }
    int n = 0;
    for (int k = 0; k < TAPN; ++k) {
        if (dense[k] != 0.f) {
            offs[t * TAPN + n] = k - 23;
            wts[t * TAPN + n] = dense[k];
            ++n;
        }
    }
    cnt[t] = n;
}

// ---------------------------------------------------------------------------
// K1: t = 2x + FIR(H) + FIR(W)  (bf16, layout [b][h][c][w])
//     anchor = BN_d(x + dwconv3_h + dwconv3_w)  (fp32, layout [b][c][h][w])
// One block per (b,c) plane; whole plane in LDS [128][160] (16-col zero pads).
// ---------------------------------------------------------------------------
__global__ __launch_bounds__(512) void k1_axial(
    const float* __restrict__ x,
    const int* __restrict__ cnt, const int* __restrict__ offs, const float* __restrict__ wts,
    const float* __restrict__ dwh, const float* __restrict__ dww,
    const float* __restrict__ dg, const float* __restrict__ db_,
    const float* __restrict__ dm, const float* __restrict__ dv,
    short* __restrict__ t_bf, float* __restrict__ anchor)
{
    __shared__ float pl[Hn][160];       // 81920 B: 16-col zero pad each side

    int bc  = blockIdx.x;               // 768
    int b   = bc / Cn;
    int c   = bc % Cn;
    int tid = threadIdx.x;

    const float* plane = x + ((long)bc << 14);

    // ----- stage whole plane (coalesced float4) -----
    const float4* p4 = (const float4*)plane;
#pragma unroll
    for (int it = 0; it < 8; ++it) {
        int idx = tid + it * 512;        // 0..4095
        int r = idx >> 5, c4 = idx & 31;
        *(float4*)&pl[r][16 + c4 * 4] = p4[idx];
    }
    // ----- zero the pads -----
#pragma unroll
    for (int it = 0; it < 2; ++it) {
        int idx = tid + it * 512;        // 0..1023
        int r = idx >> 3, pq = idx & 7;
        int col = (pq < 4) ? pq * 4 : 144 + (pq - 4) * 4;
        *(float4*)&pl[r][col] = (float4){0.f, 0.f, 0.f, 0.f};
    }

    // ----- taps: uniform loads (scalar) -----
    int cH = cnt[c * 2], cW = cnt[c * 2 + 1];
    int soH[TAPF], soW[TAPF];
    float swH[TAPF], swW[TAPF];
#pragma unroll
    for (int j = 0; j < TAPF; ++j) {
        soH[j] = offs[(c * 2) * TAPN + j];
        swH[j] = wts[(c * 2) * TAPN + j];
        soW[j] = offs[(c * 2 + 1) * TAPN + j];
        swW[j] = wts[(c * 2 + 1) * TAPN + j];
    }
    bool fast = (cH <= TAPF) && (cW <= TAPF);
#pragma unroll
    for (int j = 0; j < TAPF; ++j)
        fast = fast && (soW[j] >= -16) && (soW[j] <= 16);

    // ----- BN_d params -----
    float e0 = dwh[c * 3], e1 = dwh[c * 3 + 1], e2 = dwh[c * 3 + 2];
    float f0 = dww[c * 3], f1 = dww[c * 3 + 1], f2 = dww[c * 3 + 2];
    float dsc = dg[c] * rsqrtf(dv[c] + EPSV);
    float dof = db_[c] - dm[c] * dsc;

    __syncthreads();

    int m      = tid & 31;
    int rowgrp = tid >> 5;               // 0..15
    short* tbase = t_bf + ((long)(b * Hn) * Cn + c) * Wn;
    float* abase = anchor + ((long)bc << 14);

    for (int k = 0; k < 8; ++k) {
        int h = k * 16 + rowgrp;
        float vc0 = pl[h][16 + m];
        float vc1 = pl[h][16 + m + 32];
        float vc2 = pl[h][16 + m + 64];
        float vc3 = pl[h][16 + m + 96];
        float a0 = 2.f * vc0, a1 = 2.f * vc1, a2 = 2.f * vc2, a3 = 2.f * vc3;

        if (fast) {
#pragma unroll
            for (int j = 0; j < TAPF; ++j) {   // H taps (LDS, clamped+masked)
                int y = h + soH[j];
                float wt = (y >= 0 && y < Hn) ? swH[j] : 0.f;
                y = min(max(y, 0), Hn - 1);
                a0 += wt * pl[y][16 + m];
                a1 += wt * pl[y][16 + m + 32];
                a2 += wt * pl[y][16 + m + 64];
                a3 += wt * pl[y][16 + m + 96];
            }
#pragma unroll
            for (int j = 0; j < TAPF; ++j) {   // W taps (LDS, padded)
                int o = soW[j];
                float wt = swW[j];
                a0 += wt * pl[h][16 + m + o];
                a1 += wt * pl[h][16 + m + 32 + o];
                a2 += wt * pl[h][16 + m + 64 + o];
                a3 += wt * pl[h][16 + m + 96 + o];
            }
        } else {
            // slow fallback: correct for any runtime r (global gathers)
            const int*   goH = offs + (c * 2 + 0) * TAPN;
            const float* gwH = wts  + (c * 2 + 0) * TAPN;
            const int*   goW = offs + (c * 2 + 1) * TAPN;
            const float* gwW = wts  + (c * 2 + 1) * TAPN;
            for (int j = 0; j < cH; ++j) {
                int y = h + goH[j];
                if (y >= 0 && y < Hn) {
                    float wt = gwH[j];
                    const float* rp = plane + (y << 7);
                    a0 += wt * rp[m];
                    a1 += wt * rp[m + 32];
                    a2 += wt * rp[m + 64];
                    a3 += wt * rp[m + 96];
                }
            }
            for (int j = 0; j < cW; ++j) {
                int o = goW[j];
                float wt = gwW[j];
                const float* rp = plane + (h << 7);
#pragma unroll
                for (int q = 0; q < 4; ++q) {
                    int xw = m + 32 * q + o;
                    float v = (xw >= 0 && xw < Wn) ? rp[xw] : 0.f;
                    float* ap = (q == 0) ? &a0 : (q == 1) ? &a1 : (q == 2) ? &a2 : &a3;
                    *ap += wt * v;
                }
            }
        }

        // ----- t (bf16) store, layout [b][h][c][w] -----
        short* tp = tbase + (long)h * (Cn * Wn);
        {
            __hip_bfloat16 h0 = __float2bfloat16(a0), h1 = __float2bfloat16(a1);
            __hip_bfloat16 h2 = __float2bfloat16(a2), h3 = __float2bfloat16(a3);
            tp[m]      = *(short*)&h0;
            tp[m + 32] = *(short*)&h1;
            tp[m + 64] = *(short*)&h2;
            tp[m + 96] = *(short*)&h3;
        }

        // ----- anchor = BN_d(x + edges) -----
        int yu = (h > 0) ? h - 1 : 0;
        int yd = (h < Hn - 1) ? h + 1 : Hn - 1;
        float wu = (h > 0) ? e0 : 0.f;
        float wd = (h < Hn - 1) ? e2 : 0.f;
        float* ap = abase + (h << 7);
#pragma unroll
        for (int q = 0; q < 4; ++q) {
            int col = 16 + m + 32 * q;
            float vcq = (q == 0) ? vc0 : (q == 1) ? vc1 : (q == 2) ? vc2 : vc3;
            float vu = pl[yu][col];
            float vd = pl[yd][col];
            float vl = pl[h][col - 1];
            float vr = pl[h][col + 1];
            float edges = wu * vu + e1 * vcq + wd * vd + f0 * vl + f1 * vcq + f2 * vr;
            ap[m + 32 * q] = (vcq + edges) * dsc + dof;
        }
    }
}

// ---------------------------------------------------------------------------
// K2: out = prelu( BN_f(w @ t) + anchor )  via bf16 MFMA 16x16x32.
// Block = (b, h, half): 96 outputs x 64 pixels. 4 waves x 6 m-tiles x 1 n-tile.
// Grid 2048, LDS 33 KB -> 4 blocks/CU resident, 8 blocks/CU of work.
// ---------------------------------------------------------------------------
__global__ __launch_bounds__(256) void k2_pw(
    const short* __restrict__ t_bf, const float* __restrict__ anchor,
    const float* __restrict__ w_fuse,
    const float* __restrict__ bg, const float* __restrict__ bb,
    const float* __restrict__ bm, const float* __restrict__ bv,
    const float* __restrict__ act_a,
    float* __restrict__ out)
{
    __shared__ short wl[Cn * 100];       // [o][c], stride 100 shorts (200 B)
    __shared__ short tl[64 * 100];       // [p_local][c], stride 100 shorts
    __shared__ float sfsc[Cn], sfof[Cn], saa[Cn];

    int tid  = threadIdx.x;
    int blk  = blockIdx.x;               // 2048
    int b    = blk >> 8;
    int r    = blk & 255;
    int h    = r >> 1;
    int hb   = r & 1;                    // pixel half
    int lane = tid & 63;
    int wv   = tid >> 6;
    int n16  = lane & 15;
    int quad = lane >> 4;

    // stage w (fp32 -> bf16) -> LDS, u32 writes (c-contiguous)
    {
        uint* wdst = (uint*)wl;
        for (int e = tid; e < Cn * 48; e += 256) {
            int o = e / 48, cq = e - o * 48;
            float f0 = w_fuse[o * Cn + 2 * cq];
            float f1 = w_fuse[o * Cn + 2 * cq + 1];
            __hip_bfloat16 h0 = __float2bfloat16(f0);
            __hip_bfloat16 h1 = __float2bfloat16(f1);
            uint u = (uint)(*(unsigned short*)&h0) |
                     ((uint)(*(unsigned short*)&h1) << 16);
            wdst[o * 50 + cq] = u;
        }
    }
    // BN-fold + prelu params
    if (tid < Cn) {
        float s = bg[tid] * rsqrtf(bv[tid] + EPSV);
        sfsc[tid] = s;
        sfof[tid] = bb[tid] - bm[tid] * s;
        saa[tid]  = act_a[tid];
    }
    // stage t half-slab [96 c][64 w] -> LDS transposed [p][c] (4-ch packed b64)
    {
        const uint* trow = (const uint*)t_bf + (size_t)(b * Hn + h) * Cn * 64 + hb * 32;
#pragma unroll
        for (int rep = 0; rep < 3; ++rep) {
            int task = tid + rep * 256;  // 0..767 = 24 cgroups x 32 uint-cols
            int cg = task >> 5, j = task & 31;
            int c0 = cg * 4;
            uint v0 = trow[(c0 + 0) * 64 + j];
            uint v1 = trow[(c0 + 1) * 64 + j];
            uint v2 = trow[(c0 + 2) * 64 + j];
            uint v3 = trow[(c0 + 3) * 64 + j];
            uint2 lo, hi;
            lo.x = (v0 & 0xffffu) | (v1 << 16);
            lo.y = (v2 & 0xffffu) | (v3 << 16);
            hi.x = (v0 >> 16) | (v1 & 0xffff0000u);
            hi.y = (v2 >> 16) | (v3 & 0xffff0000u);
            *(uint2*)(tl + (2 * j) * 100 + c0)     = lo;
            *(uint2*)(tl + (2 * j + 1) * 100 + c0) = hi;
        }
    }
    __syncthreads();

    // B fragments: one 16-pixel n-tile per wave
    FragU Bf[3];
    {
        int p = wv * 16 + n16;           // local pixel 0..63
        const short* bp = tl + p * 100 + quad * 8;
#pragma unroll
        for (int kb = 0; kb < 3; ++kb) {
            Bf[kb].u2[0] = *(const uint2*)(bp + kb * 32);
            Bf[kb].u2[1] = *(const uint2*)(bp + kb * 32 + 4);
        }
    }

    floatx4 acc[6];
#pragma unroll
    for (int mt = 0; mt < 6; ++mt)
        acc[mt] = (floatx4){0.f, 0.f, 0.f, 0.f};

#pragma unroll
    for (int mt = 0; mt < 6; ++mt) {
        int o = mt * 16 + n16;
        const short* apg = wl + o * 100 + quad * 8;
        FragU Af[3];
#pragma unroll
        for (int kb = 0; kb < 3; ++kb) {
            Af[kb].u2[0] = *(const uint2*)(apg + kb * 32);
            Af[kb].u2[1] = *(const uint2*)(apg + kb * 32 + 4);
        }
#pragma unroll
        for (int kb = 0; kb < 3; ++kb)
            acc[mt] = __builtin_amdgcn_mfma_f32_16x16x32_bf16(
                Af[kb].v, Bf[kb].v, acc[mt], 0, 0, 0);
    }

    // epilogue: BN_f + anchor + prelu
    long base = (long)b * Cn * PLANE + (h << 7) + hb * 64;
    int p = wv * 16 + n16;
#pragma unroll
    for (int mt = 0; mt < 6; ++mt) {
#pragma unroll
        for (int reg = 0; reg < 4; ++reg) {
            int o = mt * 16 + quad * 4 + reg;
            long idx = base + (long)o * PLANE + p;
            float fused = acc[mt][reg] * sfsc[o] + sfof[o];
            float v = fused + anchor[idx];
            out[idx] = (v >= 0.f) ? v : saa[o] * v;
        }
    }
}

// ---------------------------------------------------------------------------
// K3: per-(b,c) plane: row means -> xh, column means -> xw
// ---------------------------------------------------------------------------
__global__ __launch_bounds__(256) void k3_means(
    const float* __restrict__ op, float* __restrict__ xh, float* __restrict__ xw)
{
    int bc = blockIdx.x;
    const float4* pl = (const float4*)(op + ((long)bc << 14));
    int tid = threadIdx.x;
    int wq = tid & 31;
    int hg = tid >> 5;
    __shared__ float cpart[8][Wn + 4];
    __shared__ float rpart[Hn];
    float4 csum = make_float4(0, 0, 0, 0);
#pragma unroll
    for (int k = 0; k < 16; ++k) {
        int h = hg * 16 + k;
        float4 v = pl[h * 32 + wq];
        csum.x += v.x; csum.y += v.y; csum.z += v.z; csum.w += v.w;
        float rs = v.x + v.y + v.z + v.w;
#pragma unroll
        for (int off = 16; off; off >>= 1) rs += __shfl_down(rs, off, 32);
        if (wq == 0) rpart[h] = rs * (1.f / Wn);
    }
    cpart[hg][wq * 4 + 0] = csum.x;
    cpart[hg][wq * 4 + 1] = csum.y;
    cpart[hg][wq * 4 + 2] = csum.z;
    cpart[hg][wq * 4 + 3] = csum.w;
    __syncthreads();
    if (tid < 128) {
        float s = 0.f;
#pragma unroll
        for (int g = 0; g < 8; ++g) s += cpart[g][tid];
        xw[bc * Wn + tid] = s * (1.f / Hn);
        xh[bc * Hn + tid] = rpart[tid];
    }
}

// ---------------------------------------------------------------------------
// K4a: y2[b][mip][p] = prelu(BN(w1 @ concat(xh,xw)))  — wide: 128 blocks.
// Block (b, pg): 16 positions. 256 thr = 16 pos x 16 c-groups (6 c each).
// ---------------------------------------------------------------------------
__global__ __launch_bounds__(256) void k4a_y2(
    const float* __restrict__ xh, const float* __restrict__ xw,
    const float* __restrict__ w1,
    const float* __restrict__ g, const float* __restrict__ bb,
    const float* __restrict__ m, const float* __restrict__ v,
    const float* __restrict__ aa,
    float* __restrict__ y2)
{
    __shared__ float w1s[8 * Cn];
    __shared__ float part[4][16][8];

    int blk = blockIdx.x;                // Bn*16
    int b   = blk >> 4;
    int pg  = blk & 15;
    int tid = threadIdx.x;
    for (int e = tid; e < 8 * Cn; e += 256) w1s[e] = w1[e];
    __syncthreads();

    int pl  = tid & 15;
    int cgl = (tid >> 4) & 3;
    int wv  = tid >> 6;
    int P   = pg * 16 + pl;              // 0..255
    int cg  = wv * 4 + cgl;              // 0..15

    const float* src = (P < Hn) ? (xh + (long)(b * Cn) * Hn + P)
                                : (xw + (long)(b * Cn) * Wn + (P - Hn));
    float acc[8];
#pragma unroll
    for (int i = 0; i < 8; ++i) acc[i] = 0.f;
#pragma unroll
    for (int ci = 0; ci < 6; ++ci) {
        int c = cg * 6 + ci;
        float yv = src[(long)c * Hn];
#pragma unroll
        for (int mip = 0; mip < 8; ++mip) acc[mip] += w1s[mip * Cn + c] * yv;
    }
    // reduce over cgl (lane bits 4-5) within wave
#pragma unroll
    for (int mip = 0; mip < 8; ++mip) {
        acc[mip] += __shfl_xor(acc[mip], 16);
        acc[mip] += __shfl_xor(acc[mip], 32);
    }
    if (cgl == 0) {
#pragma unroll
        for (int mip = 0; mip < 8; ++mip) part[wv][pl][mip] = acc[mip];
    }
    __syncthreads();

    if (tid < 128) {
        int mip = tid >> 4, pl2 = tid & 15;
        float s = part[0][pl2][mip] + part[1][pl2][mip]
                + part[2][pl2][mip] + part[3][pl2][mip];
        float sc = g[mip] * rsqrtf(v[mip] + EPSV);
        float t = (s - m[mip]) * sc + bb[mip];
        float yv = (t >= 0.f) ? t : aa[mip] * t;
        y2[((long)b * 8 + mip) * 256 + pg * 16 + pl2] = yv;
    }
}

// ---------------------------------------------------------------------------
// K4b: a_h/a_w = sigmoid(w2 @ y2)  — wide: 768 blocks, one (b,c) each.
// ---------------------------------------------------------------------------
__global__ __launch_bounds__(256) void k4b_att(
    const float* __restrict__ y2,
    const float* __restrict__ cwh, const float* __restrict__ cww,
    float* __restrict__ a_h, float* __restrict__ a_w)
{
    int bc  = blockIdx.x;                // Bn*Cn
    int b   = bc / Cn;
    int c   = bc % Cn;
    int tid = threadIdx.x;
    int p   = tid & 127;
    int isw = tid >> 7;                  // 0 -> a_h, 1 -> a_w

    const float* wsel = isw ? (cww + c * 8) : (cwh + c * 8);
    const float* ysrc = y2 + (long)b * 8 * 256 + (isw ? 128 : 0) + p;
    float s = 0.f;
#pragma unroll
    for (int mip = 0; mip < 8; ++mip) s += wsel[mip] * ysrc[mip * 256];
    float av = 1.f / (1.f + expf(-s));
    (isw ? a_w : a_h)[bc * Hn + p] = av;
}

// ---------------------------------------------------------------------------
// K5: out *= a_h[b,c,h] * a_w[b,c,w]   (in-place, float4)
// ---------------------------------------------------------------------------
__global__ __launch_bounds__(256) void k5_final(
    const float* __restrict__ a_h, const float* __restrict__ a_w,
    float* __restrict__ out)
{
    int idx = blockIdx.x * 256 + threadIdx.x;
    int e = idx * 4;
    if (e >= NIMG) return;
    int w = e & 127;
    int h = (e >> 7) & 127;
    int bc = e >> 14;
    float4 vv = *(const float4*)(out + e);
    float ah = a_h[bc * Hn + h];
    float4 aw = *(const float4*)(a_w + bc * Wn + w);
    float4 r;
    r.x = vv.x * ah * aw.x;
    r.y = vv.y * ah * aw.y;
    r.z = vv.z * ah * aw.z;
    r.w = vv.w * ah * aw.w;
    *(float4*)(out + e) = r;
}

// ---------------------------------------------------------------------------
extern "C" void kernel_launch(void* const* d_in, const int* in_sizes, int n_in,
                              void* d_out, int out_size, void* d_ws, size_t ws_size,
                              hipStream_t stream)
{
    const float* x     = (const float*)d_in[0];
    const float* r_m   = (const float*)d_in[1];
    const float* wh_m  = (const float*)d_in[2];
    const float* ww_m  = (const float*)d_in[3];
    const float* r_l   = (const float*)d_in[4];
    const float* wh_l  = (const float*)d_in[5];
    const float* ww_l  = (const float*)d_in[6];
    const float* wfuse = (const float*)d_in[7];
    const float* bnf_g = (const float*)d_in[8];
    const float* bnf_b = (const float*)d_in[9];
    const float* bnf_m = (const float*)d_in[10];
    const float* bnf_v = (const float*)d_in[11];
    const float* dg_wh = (const float*)d_in[12];
    const float* dg_ww = (const float*)d_in[13];
    const float* dg_g  = (const float*)d_in[14];
    const float* dg_b  = (const float*)d_in[15];
    const float* dg_m  = (const float*)d_in[16];
    const float* dg_v  = (const float*)d_in[17];
    const float* act_a = (const float*)d_in[18];
    const float* ca_w1 = (const float*)d_in[19];
    const float* ca_g  = (const float*)d_in[20];
    const float* ca_b  = (const float*)d_in[21];
    const float* ca_m  = (const float*)d_in[22];
    const float* ca_v  = (const float*)d_in[23];
    const float* ca_a  = (const float*)d_in[24];
    const float* ca_wh = (const float*)d_in[25];
    const float* ca_ww = (const float*)d_in[26];

    float* ws     = (float*)d_ws;
    float* anchor = ws;                          // NIMG floats
    float* xh     = anchor + (size_t)NIMG;       // 98304
    float* xw     = xh + Bn * Cn * Hn;
    float* a_h    = xw + Bn * Cn * Wn;
    float* a_w    = a_h + Bn * Cn * Hn;
    float* y2     = a_w + Bn * Cn * Wn;          // 8*8*256 = 16384
    float* wts    = y2 + Bn * 8 * 256;           // 192*48
    int*   cnt    = (int*)(wts + 2 * Cn * TAPN); // 192
    int*   offs   = cnt + 2 * Cn;                // 192*48
    short* t_bf   = (short*)(offs + 2 * Cn * TAPN); // NIMG shorts

    float* out = (float*)d_out;

    hipLaunchKernelGGL(k0_taps, dim3(1), dim3(256), 0, stream,
                       r_m, wh_m, ww_m, r_l, wh_l, ww_l, cnt, offs, wts);
    hipLaunchKernelGGL(k1_axial, dim3(Bn * Cn), dim3(512), 0, stream,
                       x, cnt, offs, wts, dg_wh, dg_ww, dg_g, dg_b, dg_m, dg_v,
                       t_bf, anchor);
    hipLaunchKernelGGL(k2_pw, dim3(Bn * Hn * 2), dim3(256), 0, stream,
                       t_bf, anchor, wfuse, bnf_g, bnf_b, bnf_m, bnf_v, act_a, out);
    hipLaunchKernelGGL(k3_means, dim3(Bn * Cn), dim3(256), 0, stream,
                       out, xh, xw);
    hipLaunchKernelGGL(k4a_y2, dim3(Bn * 16), dim3(256), 0, stream,
                       xh, xw, ca_w1, ca_g, ca_b, ca_m, ca_v, ca_a, y2);
    hipLaunchKernelGGL(k4b_att, dim3(Bn * Cn), dim3(256), 0, stream,
                       y2, ca_wh, ca_ww, a_h, a_w);
    hipLaunchKernelGGL(k5_final, dim3(NIMG / 1024), dim3(256), 0, stream,
                       a_h, a_w, out);
}

// Round 5
// 255.373 us; speedup vs baseline: 1.2531x; 1.0072x over previous
//
#include <hip/hip_runtime.h>
#include <hip/hip_bf16.h>
#include <math.h>

#define Bn 8
#define Cn 96
#define Hn 128
#define Wn 128
#define PLANE (Hn*Wn)          // 16384
#define NIMG (Bn*Cn*PLANE)     // 12582912
#define EPSV 1e-5f
#define TAPN 48
#define TAPF 8

typedef __attribute__((ext_vector_type(8))) short short8;
typedef __attribute__((ext_vector_type(4))) float floatx4;

union FragU { short8 v; uint2 u2[2]; };

// ---------------------------------------------------------------------------
// K0 (slim): merged sparse integer tap lists (zero-padded). One tiny block.
// ---------------------------------------------------------------------------
__global__ void k0_taps(
    const float* __restrict__ rm_p, const float* __restrict__ whm, const float* __restrict__ wwm,
    const float* __restrict__ rl_p, const float* __restrict__ whl, const float* __restrict__ wwl,
    int* __restrict__ cnt, int* __restrict__ offs, float* __restrict__ wts)
{
    int t = threadIdx.x;              // 0..255
    if (t >= Cn * 2) return;
    int c = t >> 1, dir = t & 1;
    for (int k = 0; k < TAPN; ++k) { offs[t * TAPN + k] = 0; wts[t * TAPN + k] = 0.f; }
    const float* tap_m = dir ? (wwm + c * 5) : (whm + c * 5);
    const float* tap_l = dir ? (wwl + c * 5) : (whl + c * 5);
    float rm = fmaxf(rm_p[0], 1.f), rl = fmaxf(rl_p[0], 1.f);
    float dense[TAPN];
    for (int k = 0; k < TAPN; ++k) dense[k] = 0.f;
    for (int pass = 0; pass < 2; ++pass) {
        float r = pass ? rl : rm;
        const float* tp = pass ? tap_l : tap_m;
        for (int i = 0; i < 5; ++i) {
            float s = (float)(i - 2) * r;
            float f = floorf(s);
            float fr = s - f;
            int fi = (int)f + 23;
            if (fi >= 0 && fi < TAPN)         dense[fi]     += tp[i] * (1.f - fr);
            if (fi + 1 >= 0 && fi + 1 < TAPN) dense[fi + 1] += tp[i] * fr;
        }
    }
    int n = 0;
    for (int k = 0; k < TAPN; ++k) {
        if (dense[k] != 0.f) {
            offs[t * TAPN + n] = k - 23;
            wts[t * TAPN + n] = dense[k];
            ++n;
        }
    }
    cnt[t] = n;
}

// ---------------------------------------------------------------------------
// K1: t = 2x + FIR(H) + FIR(W)  (bf16, layout [b][h][c][w])
//     anchor = BN_d(x + dwconv3_h + dwconv3_w)  (fp32, layout [b][c][h][w])
// One block per (b,c) plane; whole plane in LDS [128][160] (16-col zero pads).
// Also zeroes xw[bc] for k3's atomic accumulation (free, stream-ordered).
// ---------------------------------------------------------------------------
__global__ __launch_bounds__(512) void k1_axial(
    const float* __restrict__ x,
    const int* __restrict__ cnt, const int* __restrict__ offs, const float* __restrict__ wts,
    const float* __restrict__ dwh, const float* __restrict__ dww,
    const float* __restrict__ dg, const float* __restrict__ db_,
    const float* __restrict__ dm, const float* __restrict__ dv,
    short* __restrict__ t_bf, float* __restrict__ anchor,
    float* __restrict__ xw_zero)
{
    __shared__ float pl[Hn][160];       // 81920 B: 16-col zero pad each side

    int bc  = blockIdx.x;               // 768
    int b   = bc / Cn;
    int c   = bc % Cn;
    int tid = threadIdx.x;

    if (tid < Wn) xw_zero[bc * Wn + tid] = 0.f;

    const float* plane = x + ((long)bc << 14);

    // ----- stage whole plane (coalesced float4) -----
    const float4* p4 = (const float4*)plane;
#pragma unroll
    for (int it = 0; it < 8; ++it) {
        int idx = tid + it * 512;        // 0..4095
        int r = idx >> 5, c4 = idx & 31;
        *(float4*)&pl[r][16 + c4 * 4] = p4[idx];
    }
    // ----- zero the pads -----
#pragma unroll
    for (int it = 0; it < 2; ++it) {
        int idx = tid + it * 512;        // 0..1023
        int r = idx >> 3, pq = idx & 7;
        int col = (pq < 4) ? pq * 4 : 144 + (pq - 4) * 4;
        *(float4*)&pl[r][col] = (float4){0.f, 0.f, 0.f, 0.f};
    }

    // ----- taps: uniform loads (scalar) -----
    int cH = cnt[c * 2], cW = cnt[c * 2 + 1];
    int soH[TAPF], soW[TAPF];
    float swH[TAPF], swW[TAPF];
#pragma unroll
    for (int j = 0; j < TAPF; ++j) {
        soH[j] = offs[(c * 2) * TAPN + j];
        swH[j] = wts[(c * 2) * TAPN + j];
        soW[j] = offs[(c * 2 + 1) * TAPN + j];
        swW[j] = wts[(c * 2 + 1) * TAPN + j];
    }
    bool fast = (cH <= TAPF) && (cW <= TAPF);
#pragma unroll
    for (int j = 0; j < TAPF; ++j)
        fast = fast && (soW[j] >= -16) && (soW[j] <= 16);

    // ----- BN_d params -----
    float e0 = dwh[c * 3], e1 = dwh[c * 3 + 1], e2 = dwh[c * 3 + 2];
    float f0 = dww[c * 3], f1 = dww[c * 3 + 1], f2 = dww[c * 3 + 2];
    float dsc = dg[c] * rsqrtf(dv[c] + EPSV);
    float dof = db_[c] - dm[c] * dsc;

    __syncthreads();

    int m      = tid & 31;
    int rowgrp = tid >> 5;               // 0..15
    short* tbase = t_bf + ((long)(b * Hn) * Cn + c) * Wn;
    float* abase = anchor + ((long)bc << 14);

    for (int k = 0; k < 8; ++k) {
        int h = k * 16 + rowgrp;
        float vc0 = pl[h][16 + m];
        float vc1 = pl[h][16 + m + 32];
        float vc2 = pl[h][16 + m + 64];
        float vc3 = pl[h][16 + m + 96];
        float a0 = 2.f * vc0, a1 = 2.f * vc1, a2 = 2.f * vc2, a3 = 2.f * vc3;

        if (fast) {
#pragma unroll
            for (int j = 0; j < TAPF; ++j) {   // H taps (LDS, clamped+masked)
                int y = h + soH[j];
                float wt = (y >= 0 && y < Hn) ? swH[j] : 0.f;
                y = min(max(y, 0), Hn - 1);
                a0 += wt * pl[y][16 + m];
                a1 += wt * pl[y][16 + m + 32];
                a2 += wt * pl[y][16 + m + 64];
                a3 += wt * pl[y][16 + m + 96];
            }
#pragma unroll
            for (int j = 0; j < TAPF; ++j) {   // W taps (LDS, padded)
                int o = soW[j];
                float wt = swW[j];
                a0 += wt * pl[h][16 + m + o];
                a1 += wt * pl[h][16 + m + 32 + o];
                a2 += wt * pl[h][16 + m + 64 + o];
                a3 += wt * pl[h][16 + m + 96 + o];
            }
        } else {
            // slow fallback: correct for any runtime r (global gathers)
            const int*   goH = offs + (c * 2 + 0) * TAPN;
            const float* gwH = wts  + (c * 2 + 0) * TAPN;
            const int*   goW = offs + (c * 2 + 1) * TAPN;
            const float* gwW = wts  + (c * 2 + 1) * TAPN;
            for (int j = 0; j < cH; ++j) {
                int y = h + goH[j];
                if (y >= 0 && y < Hn) {
                    float wt = gwH[j];
                    const float* rp = plane + (y << 7);
                    a0 += wt * rp[m];
                    a1 += wt * rp[m + 32];
                    a2 += wt * rp[m + 64];
                    a3 += wt * rp[m + 96];
                }
            }
            for (int j = 0; j < cW; ++j) {
                int o = goW[j];
                float wt = gwW[j];
                const float* rp = plane + (h << 7);
#pragma unroll
                for (int q = 0; q < 4; ++q) {
                    int xw = m + 32 * q + o;
                    float v = (xw >= 0 && xw < Wn) ? rp[xw] : 0.f;
                    float* ap = (q == 0) ? &a0 : (q == 1) ? &a1 : (q == 2) ? &a2 : &a3;
                    *ap += wt * v;
                }
            }
        }

        // ----- t (bf16) store, layout [b][h][c][w] -----
        short* tp = tbase + (long)h * (Cn * Wn);
        {
            __hip_bfloat16 h0 = __float2bfloat16(a0), h1 = __float2bfloat16(a1);
            __hip_bfloat16 h2 = __float2bfloat16(a2), h3 = __float2bfloat16(a3);
            tp[m]      = *(short*)&h0;
            tp[m + 32] = *(short*)&h1;
            tp[m + 64] = *(short*)&h2;
            tp[m + 96] = *(short*)&h3;
        }

        // ----- anchor = BN_d(x + edges) -----
        int yu = (h > 0) ? h - 1 : 0;
        int yd = (h < Hn - 1) ? h + 1 : Hn - 1;
        float wu = (h > 0) ? e0 : 0.f;
        float wd = (h < Hn - 1) ? e2 : 0.f;
        float* ap = abase + (h << 7);
#pragma unroll
        for (int q = 0; q < 4; ++q) {
            int col = 16 + m + 32 * q;
            float vcq = (q == 0) ? vc0 : (q == 1) ? vc1 : (q == 2) ? vc2 : vc3;
            float vu = pl[yu][col];
            float vd = pl[yd][col];
            float vl = pl[h][col - 1];
            float vr = pl[h][col + 1];
            float edges = wu * vu + e1 * vcq + wd * vd + f0 * vl + f1 * vcq + f2 * vr;
            ap[m + 32 * q] = (vcq + edges) * dsc + dof;
        }
    }
}

// ---------------------------------------------------------------------------
// K2: out = prelu( BN_f(w @ t) + anchor )  via bf16 MFMA 16x16x32.
// Block = (b, h, half): 96 outputs x 64 pixels. 4 waves x 6 m-tiles x 1 n-tile.
// ---------------------------------------------------------------------------
__global__ __launch_bounds__(256) void k2_pw(
    const short* __restrict__ t_bf, const float* __restrict__ anchor,
    const float* __restrict__ w_fuse,
    const float* __restrict__ bg, const float* __restrict__ bb,
    const float* __restrict__ bm, const float* __restrict__ bv,
    const float* __restrict__ act_a,
    float* __restrict__ out)
{
    __shared__ short wl[Cn * 100];       // [o][c], stride 100 shorts (200 B)
    __shared__ short tl[64 * 100];       // [p_local][c], stride 100 shorts
    __shared__ float sfsc[Cn], sfof[Cn], saa[Cn];

    int tid  = threadIdx.x;
    int blk  = blockIdx.x;               // 2048
    int b    = blk >> 8;
    int r    = blk & 255;
    int h    = r >> 1;
    int hb   = r & 1;                    // pixel half
    int lane = tid & 63;
    int wv   = tid >> 6;
    int n16  = lane & 15;
    int quad = lane >> 4;

    // stage w (fp32 -> bf16) -> LDS, u32 writes (c-contiguous)
    {
        uint* wdst = (uint*)wl;
        for (int e = tid; e < Cn * 48; e += 256) {
            int o = e / 48, cq = e - o * 48;
            float f0 = w_fuse[o * Cn + 2 * cq];
            float f1 = w_fuse[o * Cn + 2 * cq + 1];
            __hip_bfloat16 h0 = __float2bfloat16(f0);
            __hip_bfloat16 h1 = __float2bfloat16(f1);
            uint u = (uint)(*(unsigned short*)&h0) |
                     ((uint)(*(unsigned short*)&h1) << 16);
            wdst[o * 50 + cq] = u;
        }
    }
    // BN-fold + prelu params
    if (tid < Cn) {
        float s = bg[tid] * rsqrtf(bv[tid] + EPSV);
        sfsc[tid] = s;
        sfof[tid] = bb[tid] - bm[tid] * s;
        saa[tid]  = act_a[tid];
    }
    // stage t half-slab [96 c][64 w] -> LDS transposed [p][c] (4-ch packed b64)
    {
        const uint* trow = (const uint*)t_bf + (size_t)(b * Hn + h) * Cn * 64 + hb * 32;
#pragma unroll
        for (int rep = 0; rep < 3; ++rep) {
            int task = tid + rep * 256;  // 0..767 = 24 cgroups x 32 uint-cols
            int cg = task >> 5, j = task & 31;
            int c0 = cg * 4;
            uint v0 = trow[(c0 + 0) * 64 + j];
            uint v1 = trow[(c0 + 1) * 64 + j];
            uint v2 = trow[(c0 + 2) * 64 + j];
            uint v3 = trow[(c0 + 3) * 64 + j];
            uint2 lo, hi;
            lo.x = (v0 & 0xffffu) | (v1 << 16);
            lo.y = (v2 & 0xffffu) | (v3 << 16);
            hi.x = (v0 >> 16) | (v1 & 0xffff0000u);
            hi.y = (v2 >> 16) | (v3 & 0xffff0000u);
            *(uint2*)(tl + (2 * j) * 100 + c0)     = lo;
            *(uint2*)(tl + (2 * j + 1) * 100 + c0) = hi;
        }
    }
    __syncthreads();

    // B fragments: one 16-pixel n-tile per wave
    FragU Bf[3];
    {
        int p = wv * 16 + n16;           // local pixel 0..63
        const short* bp = tl + p * 100 + quad * 8;
#pragma unroll
        for (int kb = 0; kb < 3; ++kb) {
            Bf[kb].u2[0] = *(const uint2*)(bp + kb * 32);
            Bf[kb].u2[1] = *(const uint2*)(bp + kb * 32 + 4);
        }
    }

    floatx4 acc[6];
#pragma unroll
    for (int mt = 0; mt < 6; ++mt)
        acc[mt] = (floatx4){0.f, 0.f, 0.f, 0.f};

#pragma unroll
    for (int mt = 0; mt < 6; ++mt) {
        int o = mt * 16 + n16;
        const short* apg = wl + o * 100 + quad * 8;
        FragU Af[3];
#pragma unroll
        for (int kb = 0; kb < 3; ++kb) {
            Af[kb].u2[0] = *(const uint2*)(apg + kb * 32);
            Af[kb].u2[1] = *(const uint2*)(apg + kb * 32 + 4);
        }
#pragma unroll
        for (int kb = 0; kb < 3; ++kb)
            acc[mt] = __builtin_amdgcn_mfma_f32_16x16x32_bf16(
                Af[kb].v, Bf[kb].v, acc[mt], 0, 0, 0);
    }

    // epilogue: BN_f + anchor + prelu
    long base = (long)b * Cn * PLANE + (h << 7) + hb * 64;
    int p = wv * 16 + n16;
#pragma unroll
    for (int mt = 0; mt < 6; ++mt) {
#pragma unroll
        for (int reg = 0; reg < 4; ++reg) {
            int o = mt * 16 + quad * 4 + reg;
            long idx = base + (long)o * PLANE + p;
            float fused = acc[mt][reg] * sfsc[o] + sfof[o];
            float v = fused + anchor[idx];
            out[idx] = (v >= 0.f) ? v : saa[o] * v;
        }
    }
}

// ---------------------------------------------------------------------------
// K3: 4 blocks per (b,c) plane (32 rows each): row means -> xh (direct),
// column sums -> xw via atomicAdd (xw zeroed by k1; kF divides by Hn).
// ---------------------------------------------------------------------------
__global__ __launch_bounds__(256) void k3_means(
    const float* __restrict__ op, float* __restrict__ xh, float* __restrict__ xw)
{
    int blk = blockIdx.x;                // 768*4
    int bc  = blk >> 2;
    int q   = blk & 3;
    const float4* pl = (const float4*)(op + ((long)bc << 14) + (q << 12));
    int tid = threadIdx.x;
    int wq = tid & 31;
    int hg = tid >> 5;                   // 0..7
    __shared__ float cpart[8][Wn + 4];
    __shared__ float rpart[32];
    float4 csum = make_float4(0, 0, 0, 0);
#pragma unroll
    for (int k = 0; k < 4; ++k) {
        int hl = hg * 4 + k;             // local row 0..31
        float4 v = pl[hl * 32 + wq];
        csum.x += v.x; csum.y += v.y; csum.z += v.z; csum.w += v.w;
        float rs = v.x + v.y + v.z + v.w;
#pragma unroll
        for (int off = 16; off; off >>= 1) rs += __shfl_down(rs, off, 32);
        if (wq == 0) rpart[hl] = rs * (1.f / Wn);
    }
    cpart[hg][wq * 4 + 0] = csum.x;
    cpart[hg][wq * 4 + 1] = csum.y;
    cpart[hg][wq * 4 + 2] = csum.z;
    cpart[hg][wq * 4 + 3] = csum.w;
    __syncthreads();
    if (tid < 128) {
        float s = 0.f;
#pragma unroll
        for (int g = 0; g < 8; ++g) s += cpart[g][tid];
        atomicAdd(&xw[bc * Wn + tid], s);
    }
    if (tid < 32) xh[bc * Hn + q * 32 + tid] = rpart[tid];
}

// ---------------------------------------------------------------------------
// KF: fused coord-attention MLP + scale.  One block per (b,c) plane.
// Thread p computes y2[:,p] (96-dot over L2-resident xh/xw), BN+prelu,
// dot with cwh/cww, sigmoid -> LDS; then block scales its out plane in place.
// xw holds RAW column sums -> divide by Hn at load.
// ---------------------------------------------------------------------------
__global__ __launch_bounds__(256) void kf_att_scale(
    const float* __restrict__ xh, const float* __restrict__ xw,
    const float* __restrict__ w1,
    const float* __restrict__ g, const float* __restrict__ bb,
    const float* __restrict__ m, const float* __restrict__ v,
    const float* __restrict__ aa,
    const float* __restrict__ cwh, const float* __restrict__ cww,
    float* __restrict__ out)
{
    __shared__ float w1s[8 * Cn];
    __shared__ float sah[Hn];
    __shared__ float saw[Wn];

    int bc  = blockIdx.x;                // 768
    int b   = bc / Cn;
    int c   = bc % Cn;
    int p   = threadIdx.x;               // 0..255

    for (int e = p; e < 8 * Cn; e += 256) w1s[e] = w1[e];
    __syncthreads();

    bool isH = (p < Hn);
    const float* src = isH ? (xh + ((long)b * Cn) * Hn + p)
                           : (xw + ((long)b * Cn) * Wn + (p - Hn));
    float scale = isH ? 1.f : (1.f / Hn);

    float acc[8];
#pragma unroll
    for (int i = 0; i < 8; ++i) acc[i] = 0.f;
    for (int cc = 0; cc < Cn; ++cc) {
        float yv = src[(long)cc * Hn] * scale;
#pragma unroll
        for (int mip = 0; mip < 8; ++mip) acc[mip] += w1s[mip * Cn + cc] * yv;
    }
    const float* wsel = isH ? (cwh + c * 8) : (cww + c * 8);
    float s = 0.f;
#pragma unroll
    for (int mip = 0; mip < 8; ++mip) {
        float sc = g[mip] * rsqrtf(v[mip] + EPSV);
        float t = (acc[mip] - m[mip]) * sc + bb[mip];
        float yv = (t >= 0.f) ? t : aa[mip] * t;
        s += wsel[mip] * yv;
    }
    float av = 1.f / (1.f + expf(-s));
    if (isH) sah[p] = av; else saw[p - Hn] = av;
    __syncthreads();

    float4* p4 = (float4*)(out + ((long)bc << 14));
#pragma unroll
    for (int it = 0; it < 16; ++it) {
        int idx = p + it * 256;          // 0..4095 float4s
        int h = idx >> 5;
        int w4 = idx & 31;
        float4 vv = p4[idx];
        float ah = sah[h];
        float4 aw = *(float4*)&saw[w4 * 4];
        float4 r;
        r.x = vv.x * ah * aw.x;
        r.y = vv.y * ah * aw.y;
        r.z = vv.z * ah * aw.z;
        r.w = vv.w * ah * aw.w;
        p4[idx] = r;
    }
}

// ---------------------------------------------------------------------------
extern "C" void kernel_launch(void* const* d_in, const int* in_sizes, int n_in,
                              void* d_out, int out_size, void* d_ws, size_t ws_size,
                              hipStream_t stream)
{
    const float* x     = (const float*)d_in[0];
    const float* r_m   = (const float*)d_in[1];
    const float* wh_m  = (const float*)d_in[2];
    const float* ww_m  = (const float*)d_in[3];
    const float* r_l   = (const float*)d_in[4];
    const float* wh_l  = (const float*)d_in[5];
    const float* ww_l  = (const float*)d_in[6];
    const float* wfuse = (const float*)d_in[7];
    const float* bnf_g = (const float*)d_in[8];
    const float* bnf_b = (const float*)d_in[9];
    const float* bnf_m = (const float*)d_in[10];
    const float* bnf_v = (const float*)d_in[11];
    const float* dg_wh = (const float*)d_in[12];
    const float* dg_ww = (const float*)d_in[13];
    const float* dg_g  = (const float*)d_in[14];
    const float* dg_b  = (const float*)d_in[15];
    const float* dg_m  = (const float*)d_in[16];
    const float* dg_v  = (const float*)d_in[17];
    const float* act_a = (const float*)d_in[18];
    const float* ca_w1 = (const float*)d_in[19];
    const float* ca_g  = (const float*)d_in[20];
    const float* ca_b  = (const float*)d_in[21];
    const float* ca_m  = (const float*)d_in[22];
    const float* ca_v  = (const float*)d_in[23];
    const float* ca_a  = (const float*)d_in[24];
    const float* ca_wh = (const float*)d_in[25];
    const float* ca_ww = (const float*)d_in[26];

    float* ws     = (float*)d_ws;
    float* anchor = ws;                          // NIMG floats
    float* xh     = anchor + (size_t)NIMG;       // 98304
    float* xw     = xh + Bn * Cn * Hn;           // 98304
    float* wts    = xw + Bn * Cn * Wn;           // 192*48
    int*   cnt    = (int*)(wts + 2 * Cn * TAPN); // 192
    int*   offs   = cnt + 2 * Cn;                // 192*48
    short* t_bf   = (short*)(offs + 2 * Cn * TAPN); // NIMG shorts

    float* out = (float*)d_out;

    hipLaunchKernelGGL(k0_taps, dim3(1), dim3(256), 0, stream,
                       r_m, wh_m, ww_m, r_l, wh_l, ww_l, cnt, offs, wts);
    hipLaunchKernelGGL(k1_axial, dim3(Bn * Cn), dim3(512), 0, stream,
                       x, cnt, offs, wts, dg_wh, dg_ww, dg_g, dg_b, dg_m, dg_v,
                       t_bf, anchor, xw);
    hipLaunchKernelGGL(k2_pw, dim3(Bn * Hn * 2), dim3(256), 0, stream,
                       t_bf, anchor, wfuse, bnf_g, bnf_b, bnf_m, bnf_v, act_a, out);
    hipLaunchKernelGGL(k3_means, dim3(Bn * Cn * 4), dim3(256), 0, stream,
                       out, xh, xw);
    hipLaunchKernelGGL(kf_att_scale, dim3(Bn * Cn), dim3(256), 0, stream,
                       xh, xw, ca_w1, ca_g, ca_b, ca_m, ca_v, ca_a, ca_wh, ca_ww,
                       out);
}

// Round 6
// 229.073 us; speedup vs baseline: 1.3969x; 1.1148x over previous
//
#include <hip/hip_runtime.h>
#include <hip/hip_bf16.h>
#include <math.h>

#define Bn 8
#define Cn 96
#define Hn 128
#define Wn 128
#define PLANE (Hn*Wn)          // 16384
#define NIMG (Bn*Cn*PLANE)     // 12582912
#define EPSV 1e-5f
#define TAPN 48
#define TAPF 8

typedef __attribute__((ext_vector_type(8))) short short8;
typedef __attribute__((ext_vector_type(4))) float floatx4;

union FragU { short8 v; uint2 u2[2]; };

// ---------------------------------------------------------------------------
// K0: merged sparse integer tap lists. One block, 192 active threads.
// dense[] lives in LDS (rule #20: runtime-indexed per-thread arrays go to
// scratch -> was 103 us; LDS version is ~5 cy per access).
// Each thread writes its FULL 48-slot offs/wts row (compacted + zero pad),
// so no separate zero-init pass and no cross-thread ordering.
// ---------------------------------------------------------------------------
__global__ __launch_bounds__(256) void k0_taps(
    const float* __restrict__ rm_p, const float* __restrict__ whm, const float* __restrict__ wwm,
    const float* __restrict__ rl_p, const float* __restrict__ whl, const float* __restrict__ wwl,
    int* __restrict__ cnt, int* __restrict__ offs, float* __restrict__ wts)
{
    __shared__ float dense[2 * Cn][TAPN + 1];   // 192 x 49 floats = 37632 B

    int t = threadIdx.x;              // 0..255
    // zero LDS (all 256 threads)
    for (int e = t; e < 2 * Cn * (TAPN + 1); e += 256)
        ((float*)dense)[e] = 0.f;
    __syncthreads();

    if (t >= Cn * 2) return;
    int c = t >> 1, dir = t & 1;
    const float* tap_m = dir ? (wwm + c * 5) : (whm + c * 5);
    const float* tap_l = dir ? (wwl + c * 5) : (whl + c * 5);
    float rm = fmaxf(rm_p[0], 1.f), rl = fmaxf(rl_p[0], 1.f);
    for (int pass = 0; pass < 2; ++pass) {
        float r = pass ? rl : rm;
        const float* tp = pass ? tap_l : tap_m;
        for (int i = 0; i < 5; ++i) {
            float s = (float)(i - 2) * r;
            float f = floorf(s);
            float fr = s - f;
            int fi = (int)f + 23;
            if (fi >= 0 && fi < TAPN)         dense[t][fi]     += tp[i] * (1.f - fr);
            if (fi + 1 >= 0 && fi + 1 < TAPN) dense[t][fi + 1] += tp[i] * fr;
        }
    }
    // compact row t -> global, writing all 48 slots (entries then zeros)
    int n = 0;
    int*   orow = offs + t * TAPN;
    float* wrow = wts  + t * TAPN;
    for (int k = 0; k < TAPN; ++k) {
        float wv = dense[t][k];
        if (wv != 0.f) { orow[n] = k - 23; wrow[n] = wv; ++n; }
    }
    cnt[t] = n;
    for (int k = n; k < TAPN; ++k) { orow[k] = 0; wrow[k] = 0.f; }
}

// ---------------------------------------------------------------------------
// K1: t = 2x + FIR(H) + FIR(W)  (bf16, layout [b][h][c][w])
//     anchor = BN_d(x + dwconv3_h + dwconv3_w)  (fp32, layout [b][c][h][w])
// One block per (b,c) plane; whole plane in LDS [128][160] (16-col zero pads).
// Also zeroes xw[bc] for k3's atomic accumulation (free, stream-ordered).
// ---------------------------------------------------------------------------
__global__ __launch_bounds__(512) void k1_axial(
    const float* __restrict__ x,
    const int* __restrict__ cnt, const int* __restrict__ offs, const float* __restrict__ wts,
    const float* __restrict__ dwh, const float* __restrict__ dww,
    const float* __restrict__ dg, const float* __restrict__ db_,
    const float* __restrict__ dm, const float* __restrict__ dv,
    short* __restrict__ t_bf, float* __restrict__ anchor,
    float* __restrict__ xw_zero)
{
    __shared__ float pl[Hn][160];       // 81920 B: 16-col zero pad each side

    int bc  = blockIdx.x;               // 768
    int b   = bc / Cn;
    int c   = bc % Cn;
    int tid = threadIdx.x;

    if (tid < Wn) xw_zero[bc * Wn + tid] = 0.f;

    const float* plane = x + ((long)bc << 14);

    // ----- stage whole plane (coalesced float4) -----
    const float4* p4 = (const float4*)plane;
#pragma unroll
    for (int it = 0; it < 8; ++it) {
        int idx = tid + it * 512;        // 0..4095
        int r = idx >> 5, c4 = idx & 31;
        *(float4*)&pl[r][16 + c4 * 4] = p4[idx];
    }
    // ----- zero the pads -----
#pragma unroll
    for (int it = 0; it < 2; ++it) {
        int idx = tid + it * 512;        // 0..1023
        int r = idx >> 3, pq = idx & 7;
        int col = (pq < 4) ? pq * 4 : 144 + (pq - 4) * 4;
        *(float4*)&pl[r][col] = (float4){0.f, 0.f, 0.f, 0.f};
    }

    // ----- taps: uniform loads (scalar) -----
    int cH = cnt[c * 2], cW = cnt[c * 2 + 1];
    int soH[TAPF], soW[TAPF];
    float swH[TAPF], swW[TAPF];
#pragma unroll
    for (int j = 0; j < TAPF; ++j) {
        soH[j] = offs[(c * 2) * TAPN + j];
        swH[j] = wts[(c * 2) * TAPN + j];
        soW[j] = offs[(c * 2 + 1) * TAPN + j];
        swW[j] = wts[(c * 2 + 1) * TAPN + j];
    }
    bool fast = (cH <= TAPF) && (cW <= TAPF);
#pragma unroll
    for (int j = 0; j < TAPF; ++j)
        fast = fast && (soW[j] >= -16) && (soW[j] <= 16);

    // ----- BN_d params -----
    float e0 = dwh[c * 3], e1 = dwh[c * 3 + 1], e2 = dwh[c * 3 + 2];
    float f0 = dww[c * 3], f1 = dww[c * 3 + 1], f2 = dww[c * 3 + 2];
    float dsc = dg[c] * rsqrtf(dv[c] + EPSV);
    float dof = db_[c] - dm[c] * dsc;

    __syncthreads();

    int m      = tid & 31;
    int rowgrp = tid >> 5;               // 0..15
    short* tbase = t_bf + ((long)(b * Hn) * Cn + c) * Wn;
    float* abase = anchor + ((long)bc << 14);

    for (int k = 0; k < 8; ++k) {
        int h = k * 16 + rowgrp;
        float vc0 = pl[h][16 + m];
        float vc1 = pl[h][16 + m + 32];
        float vc2 = pl[h][16 + m + 64];
        float vc3 = pl[h][16 + m + 96];
        float a0 = 2.f * vc0, a1 = 2.f * vc1, a2 = 2.f * vc2, a3 = 2.f * vc3;

        if (fast) {
#pragma unroll
            for (int j = 0; j < TAPF; ++j) {   // H taps (LDS, clamped+masked)
                int y = h + soH[j];
                float wt = (y >= 0 && y < Hn) ? swH[j] : 0.f;
                y = min(max(y, 0), Hn - 1);
                a0 += wt * pl[y][16 + m];
                a1 += wt * pl[y][16 + m + 32];
                a2 += wt * pl[y][16 + m + 64];
                a3 += wt * pl[y][16 + m + 96];
            }
#pragma unroll
            for (int j = 0; j < TAPF; ++j) {   // W taps (LDS, padded)
                int o = soW[j];
                float wt = swW[j];
                a0 += wt * pl[h][16 + m + o];
                a1 += wt * pl[h][16 + m + 32 + o];
                a2 += wt * pl[h][16 + m + 64 + o];
                a3 += wt * pl[h][16 + m + 96 + o];
            }
        } else {
            // slow fallback: correct for any runtime r (global gathers)
            const int*   goH = offs + (c * 2 + 0) * TAPN;
            const float* gwH = wts  + (c * 2 + 0) * TAPN;
            const int*   goW = offs + (c * 2 + 1) * TAPN;
            const float* gwW = wts  + (c * 2 + 1) * TAPN;
            for (int j = 0; j < cH; ++j) {
                int y = h + goH[j];
                if (y >= 0 && y < Hn) {
                    float wt = gwH[j];
                    const float* rp = plane + (y << 7);
                    a0 += wt * rp[m];
                    a1 += wt * rp[m + 32];
                    a2 += wt * rp[m + 64];
                    a3 += wt * rp[m + 96];
                }
            }
            for (int j = 0; j < cW; ++j) {
                int o = goW[j];
                float wt = gwW[j];
                const float* rp = plane + (h << 7);
#pragma unroll
                for (int q = 0; q < 4; ++q) {
                    int xw = m + 32 * q + o;
                    float v = (xw >= 0 && xw < Wn) ? rp[xw] : 0.f;
                    float* ap = (q == 0) ? &a0 : (q == 1) ? &a1 : (q == 2) ? &a2 : &a3;
                    *ap += wt * v;
                }
            }
        }

        // ----- t (bf16) store, layout [b][h][c][w] -----
        short* tp = tbase + (long)h * (Cn * Wn);
        {
            __hip_bfloat16 h0 = __float2bfloat16(a0), h1 = __float2bfloat16(a1);
            __hip_bfloat16 h2 = __float2bfloat16(a2), h3 = __float2bfloat16(a3);
            tp[m]      = *(short*)&h0;
            tp[m + 32] = *(short*)&h1;
            tp[m + 64] = *(short*)&h2;
            tp[m + 96] = *(short*)&h3;
        }

        // ----- anchor = BN_d(x + edges) -----
        int yu = (h > 0) ? h - 1 : 0;
        int yd = (h < Hn - 1) ? h + 1 : Hn - 1;
        float wu = (h > 0) ? e0 : 0.f;
        float wd = (h < Hn - 1) ? e2 : 0.f;
        float* ap = abase + (h << 7);
#pragma unroll
        for (int q = 0; q < 4; ++q) {
            int col = 16 + m + 32 * q;
            float vcq = (q == 0) ? vc0 : (q == 1) ? vc1 : (q == 2) ? vc2 : vc3;
            float vu = pl[yu][col];
            float vd = pl[yd][col];
            float vl = pl[h][col - 1];
            float vr = pl[h][col + 1];
            float edges = wu * vu + e1 * vcq + wd * vd + f0 * vl + f1 * vcq + f2 * vr;
            ap[m + 32 * q] = (vcq + edges) * dsc + dof;
        }
    }
}

// ---------------------------------------------------------------------------
// K2: out = prelu( BN_f(w @ t) + anchor )  via bf16 MFMA 16x16x32.
// Block = (b, h, half): 96 outputs x 64 pixels. 4 waves x 6 m-tiles x 1 n-tile.
// ---------------------------------------------------------------------------
__global__ __launch_bounds__(256) void k2_pw(
    const short* __restrict__ t_bf, const float* __restrict__ anchor,
    const float* __restrict__ w_fuse,
    const float* __restrict__ bg, const float* __restrict__ bb,
    const float* __restrict__ bm, const float* __restrict__ bv,
    const float* __restrict__ act_a,
    float* __restrict__ out)
{
    __shared__ short wl[Cn * 100];       // [o][c], stride 100 shorts (200 B)
    __shared__ short tl[64 * 100];       // [p_local][c], stride 100 shorts
    __shared__ float sfsc[Cn], sfof[Cn], saa[Cn];

    int tid  = threadIdx.x;
    int blk  = blockIdx.x;               // 2048
    int b    = blk >> 8;
    int r    = blk & 255;
    int h    = r >> 1;
    int hb   = r & 1;                    // pixel half
    int lane = tid & 63;
    int wv   = tid >> 6;
    int n16  = lane & 15;
    int quad = lane >> 4;

    // stage w (fp32 -> bf16) -> LDS, u32 writes (c-contiguous)
    {
        uint* wdst = (uint*)wl;
        for (int e = tid; e < Cn * 48; e += 256) {
            int o = e / 48, cq = e - o * 48;
            float f0 = w_fuse[o * Cn + 2 * cq];
            float f1 = w_fuse[o * Cn + 2 * cq + 1];
            __hip_bfloat16 h0 = __float2bfloat16(f0);
            __hip_bfloat16 h1 = __float2bfloat16(f1);
            uint u = (uint)(*(unsigned short*)&h0) |
                     ((uint)(*(unsigned short*)&h1) << 16);
            wdst[o * 50 + cq] = u;
        }
    }
    // BN-fold + prelu params
    if (tid < Cn) {
        float s = bg[tid] * rsqrtf(bv[tid] + EPSV);
        sfsc[tid] = s;
        sfof[tid] = bb[tid] - bm[tid] * s;
        saa[tid]  = act_a[tid];
    }
    // stage t half-slab [96 c][64 w] -> LDS transposed [p][c] (4-ch packed b64)
    {
        const uint* trow = (const uint*)t_bf + (size_t)(b * Hn + h) * Cn * 64 + hb * 32;
#pragma unroll
        for (int rep = 0; rep < 3; ++rep) {
            int task = tid + rep * 256;  // 0..767 = 24 cgroups x 32 uint-cols
            int cg = task >> 5, j = task & 31;
            int c0 = cg * 4;
            uint v0 = trow[(c0 + 0) * 64 + j];
            uint v1 = trow[(c0 + 1) * 64 + j];
            uint v2 = trow[(c0 + 2) * 64 + j];
            uint v3 = trow[(c0 + 3) * 64 + j];
            uint2 lo, hi;
            lo.x = (v0 & 0xffffu) | (v1 << 16);
            lo.y = (v2 & 0xffffu) | (v3 << 16);
            hi.x = (v0 >> 16) | (v1 & 0xffff0000u);
            hi.y = (v2 >> 16) | (v3 & 0xffff0000u);
            *(uint2*)(tl + (2 * j) * 100 + c0)     = lo;
            *(uint2*)(tl + (2 * j + 1) * 100 + c0) = hi;
        }
    }
    __syncthreads();

    // B fragments: one 16-pixel n-tile per wave
    FragU Bf[3];
    {
        int p = wv * 16 + n16;           // local pixel 0..63
        const short* bp = tl + p * 100 + quad * 8;
#pragma unroll
        for (int kb = 0; kb < 3; ++kb) {
            Bf[kb].u2[0] = *(const uint2*)(bp + kb * 32);
            Bf[kb].u2[1] = *(const uint2*)(bp + kb * 32 + 4);
        }
    }

    floatx4 acc[6];
#pragma unroll
    for (int mt = 0; mt < 6; ++mt)
        acc[mt] = (floatx4){0.f, 0.f, 0.f, 0.f};

#pragma unroll
    for (int mt = 0; mt < 6; ++mt) {
        int o = mt * 16 + n16;
        const short* apg = wl + o * 100 + quad * 8;
        FragU Af[3];
#pragma unroll
        for (int kb = 0; kb < 3; ++kb) {
            Af[kb].u2[0] = *(const uint2*)(apg + kb * 32);
            Af[kb].u2[1] = *(const uint2*)(apg + kb * 32 + 4);
        }
#pragma unroll
        for (int kb = 0; kb < 3; ++kb)
            acc[mt] = __builtin_amdgcn_mfma_f32_16x16x32_bf16(
                Af[kb].v, Bf[kb].v, acc[mt], 0, 0, 0);
    }

    // epilogue: BN_f + anchor + prelu
    long base = (long)b * Cn * PLANE + (h << 7) + hb * 64;
    int p = wv * 16 + n16;
#pragma unroll
    for (int mt = 0; mt < 6; ++mt) {
#pragma unroll
        for (int reg = 0; reg < 4; ++reg) {
            int o = mt * 16 + quad * 4 + reg;
            long idx = base + (long)o * PLANE + p;
            float fused = acc[mt][reg] * sfsc[o] + sfof[o];
            float v = fused + anchor[idx];
            out[idx] = (v >= 0.f) ? v : saa[o] * v;
        }
    }
}

// ---------------------------------------------------------------------------
// K3: 4 blocks per (b,c) plane (32 rows each): row means -> xh (direct),
// column sums -> xw via atomicAdd (xw zeroed by k1; kF divides by Hn).
// ---------------------------------------------------------------------------
__global__ __launch_bounds__(256) void k3_means(
    const float* __restrict__ op, float* __restrict__ xh, float* __restrict__ xw)
{
    int blk = blockIdx.x;                // 768*4
    int bc  = blk >> 2;
    int q   = blk & 3;
    const float4* pl = (const float4*)(op + ((long)bc << 14) + (q << 12));
    int tid = threadIdx.x;
    int wq = tid & 31;
    int hg = tid >> 5;                   // 0..7
    __shared__ float cpart[8][Wn + 4];
    __shared__ float rpart[32];
    float4 csum = make_float4(0, 0, 0, 0);
#pragma unroll
    for (int k = 0; k < 4; ++k) {
        int hl = hg * 4 + k;             // local row 0..31
        float4 v = pl[hl * 32 + wq];
        csum.x += v.x; csum.y += v.y; csum.z += v.z; csum.w += v.w;
        float rs = v.x + v.y + v.z + v.w;
#pragma unroll
        for (int off = 16; off; off >>= 1) rs += __shfl_down(rs, off, 32);
        if (wq == 0) rpart[hl] = rs * (1.f / Wn);
    }
    cpart[hg][wq * 4 + 0] = csum.x;
    cpart[hg][wq * 4 + 1] = csum.y;
    cpart[hg][wq * 4 + 2] = csum.z;
    cpart[hg][wq * 4 + 3] = csum.w;
    __syncthreads();
    if (tid < 128) {
        float s = 0.f;
#pragma unroll
        for (int g = 0; g < 8; ++g) s += cpart[g][tid];
        atomicAdd(&xw[bc * Wn + tid], s);
    }
    if (tid < 32) xh[bc * Hn + q * 32 + tid] = rpart[tid];
}

// ---------------------------------------------------------------------------
// KF: fused coord-attention MLP + scale.  One block per (b,c) plane.
// Thread p computes y2[:,p] (96-dot over L2-resident xh/xw), BN+prelu,
// dot with cwh/cww, sigmoid -> LDS; then block scales its out plane in place.
// xw holds RAW column sums -> divide by Hn at load.
// ---------------------------------------------------------------------------
__global__ __launch_bounds__(256) void kf_att_scale(
    const float* __restrict__ xh, const float* __restrict__ xw,
    const float* __restrict__ w1,
    const float* __restrict__ g, const float* __restrict__ bb,
    const float* __restrict__ m, const float* __restrict__ v,
    const float* __restrict__ aa,
    const float* __restrict__ cwh, const float* __restrict__ cww,
    float* __restrict__ out)
{
    __shared__ float w1s[8 * Cn];
    __shared__ float sah[Hn];
    __shared__ float saw[Wn];

    int bc  = blockIdx.x;                // 768
    int b   = bc / Cn;
    int c   = bc % Cn;
    int p   = threadIdx.x;               // 0..255

    for (int e = p; e < 8 * Cn; e += 256) w1s[e] = w1[e];
    __syncthreads();

    bool isH = (p < Hn);
    const float* src = isH ? (xh + ((long)b * Cn) * Hn + p)
                           : (xw + ((long)b * Cn) * Wn + (p - Hn));
    float scale = isH ? 1.f : (1.f / Hn);

    float acc[8];
#pragma unroll
    for (int i = 0; i < 8; ++i) acc[i] = 0.f;
    for (int cc = 0; cc < Cn; ++cc) {
        float yv = src[(long)cc * Hn] * scale;
#pragma unroll
        for (int mip = 0; mip < 8; ++mip) acc[mip] += w1s[mip * Cn + cc] * yv;
    }
    const float* wsel = isH ? (cwh + c * 8) : (cww + c * 8);
    float s = 0.f;
#pragma unroll
    for (int mip = 0; mip < 8; ++mip) {
        float sc = g[mip] * rsqrtf(v[mip] + EPSV);
        float t = (acc[mip] - m[mip]) * sc + bb[mip];
        float yv = (t >= 0.f) ? t : aa[mip] * t;
        s += wsel[mip] * yv;
    }
    float av = 1.f / (1.f + expf(-s));
    if (isH) sah[p] = av; else saw[p - Hn] = av;
    __syncthreads();

    float4* p4 = (float4*)(out + ((long)bc << 14));
#pragma unroll
    for (int it = 0; it < 16; ++it) {
        int idx = p + it * 256;          // 0..4095 float4s
        int h = idx >> 5;
        int w4 = idx & 31;
        float4 vv = p4[idx];
        float ah = sah[h];
        float4 aw = *(float4*)&saw[w4 * 4];
        float4 r;
        r.x = vv.x * ah * aw.x;
        r.y = vv.y * ah * aw.y;
        r.z = vv.z * ah * aw.z;
        r.w = vv.w * ah * aw.w;
        p4[idx] = r;
    }
}

// ---------------------------------------------------------------------------
extern "C" void kernel_launch(void* const* d_in, const int* in_sizes, int n_in,
                              void* d_out, int out_size, void* d_ws, size_t ws_size,
                              hipStream_t stream)
{
    const float* x     = (const float*)d_in[0];
    const float* r_m   = (const float*)d_in[1];
    const float* wh_m  = (const float*)d_in[2];
    const float* ww_m  = (const float*)d_in[3];
    const float* r_l   = (const float*)d_in[4];
    const float* wh_l  = (const float*)d_in[5];
    const float* ww_l  = (const float*)d_in[6];
    const float* wfuse = (const float*)d_in[7];
    const float* bnf_g = (const float*)d_in[8];
    const float* bnf_b = (const float*)d_in[9];
    const float* bnf_m = (const float*)d_in[10];
    const float* bnf_v = (const float*)d_in[11];
    const float* dg_wh = (const float*)d_in[12];
    const float* dg_ww = (const float*)d_in[13];
    const float* dg_g  = (const float*)d_in[14];
    const float* dg_b  = (const float*)d_in[15];
    const float* dg_m  = (const float*)d_in[16];
    const float* dg_v  = (const float*)d_in[17];
    const float* act_a = (const float*)d_in[18];
    const float* ca_w1 = (const float*)d_in[19];
    const float* ca_g  = (const float*)d_in[20];
    const float* ca_b  = (const float*)d_in[21];
    const float* ca_m  = (const float*)d_in[22];
    const float* ca_v  = (const float*)d_in[23];
    const float* ca_a  = (const float*)d_in[24];
    const float* ca_wh = (const float*)d_in[25];
    const float* ca_ww = (const float*)d_in[26];

    float* ws     = (float*)d_ws;
    float* anchor = ws;                          // NIMG floats
    float* xh     = anchor + (size_t)NIMG;       // 98304
    float* xw     = xh + Bn * Cn * Hn;           // 98304
    float* wts    = xw + Bn * Cn * Wn;           // 192*48
    int*   cnt    = (int*)(wts + 2 * Cn * TAPN); // 192
    int*   offs   = cnt + 2 * Cn;                // 192*48
    short* t_bf   = (short*)(offs + 2 * Cn * TAPN); // NIMG shorts

    float* out = (float*)d_out;

    hipLaunchKernelGGL(k0_taps, dim3(1), dim3(256), 0, stream,
                       r_m, wh_m, ww_m, r_l, wh_l, ww_l, cnt, offs, wts);
    hipLaunchKernelGGL(k1_axial, dim3(Bn * Cn), dim3(512), 0, stream,
                       x, cnt, offs, wts, dg_wh, dg_ww, dg_g, dg_b, dg_m, dg_v,
                       t_bf, anchor, xw);
    hipLaunchKernelGGL(k2_pw, dim3(Bn * Hn * 2), dim3(256), 0, stream,
                       t_bf, anchor, wfuse, bnf_g, bnf_b, bnf_m, bnf_v, act_a, out);
    hipLaunchKernelGGL(k3_means, dim3(Bn * Cn * 4), dim3(256), 0, stream,
                       out, xh, xw);
    hipLaunchKernelGGL(kf_att_scale, dim3(Bn * Cn), dim3(256), 0, stream,
                       xh, xw, ca_w1, ca_g, ca_b, ca_m, ca_v, ca_a, ca_wh, ca_ww,
                       out);
}